// Round 7
// baseline (493.735 us; speedup 1.0000x reference)
//
#include <hip/hip_runtime.h>

#define NN 50000
#define NE 800000
#define DD 128
#define PEW 98
#define KPE 226
#define WSLOT 32768   // bf16 elements per weight slot (128 n x 256 k)
#define NB 49         // scan blocks per level: ceil(NN/1024)
#define GX 782        // ceil(NN/64) gemm row-tiles
#define HIST8B 391    // ceil(NE/(256*8)) hist blocks per level (8 edges/thread)
#define FILLB 782     // ceil(NE/(256*4)) fill blocks per level
#define PREPXB 6250   // NN*256/(256*8) prepx blocks (8 elems/thread)
#define PREPB 48      // 6 slots x 8 tile-blocks
#define AGGB 12500    // ceil(NN/4): 1 wave per node, 4 nodes/block

typedef __attribute__((ext_vector_type(8))) short short8;
typedef __attribute__((ext_vector_type(4))) float float4v;

// Kept so anything that looks up the original kernel name still finds a symbol.
__global__ void GraphTrajSTEncoder_67362267070834_kernel() {}

// ---------------- dtype helpers ----------------

__device__ __forceinline__ float bfbits_to_f(unsigned int u16) {
    unsigned int v = u16 << 16;
    float f;
    __builtin_memcpy(&f, &v, 4);
    return f;
}

__device__ __forceinline__ float bits_to_f(unsigned int v) {
    float f;
    __builtin_memcpy(&f, &v, 4);
    return f;
}

__device__ __forceinline__ int f_as_i(float f) {
    int i;
    __builtin_memcpy(&i, &f, 4);
    return i;
}

__device__ __forceinline__ unsigned short f_to_bfbits(float f) {
    unsigned int b;
    __builtin_memcpy(&b, &f, 4);
    unsigned int r = b + 0x7FFFu + ((b >> 16) & 1u);   // round to nearest even
    return (unsigned short)(r >> 16);
}

__device__ __forceinline__ float ldf(const void* p, int i, int isbf) {
    if (isbf) return bfbits_to_f(((const unsigned short*)p)[i]);
    return ((const float*)p)[i];
}

// ---------------- dispatch 1: dtype detect + zero degree arrays ----------------
__global__ __launch_bounds__(256)
void k_detect0(const unsigned int* xw, int* flag, float* dout_sentinel,
               int* deg0, int* deg1) {
    if (blockIdx.x == 0) {
        __shared__ int cnt;
        if (threadIdx.x == 0) cnt = 0;
        __syncthreads();
        unsigned int w = xw[threadIdx.x];
        unsigned int e = (w >> 7) & 0xFFu;
        atomicAdd(&cnt, (e >= 100u && e <= 150u) ? 1 : 0);
        __syncthreads();
        if (threadIdx.x == 0) {
            flag[0] = (cnt >= 128) ? 1 : 0;
            dout_sentinel[0] = 1.0e6f;
        }
    } else {
        int i = (blockIdx.x - 1) * 256 + threadIdx.x;
        if (i < NN) deg0[i] = 0;
        else if (i < 2 * NN) deg1[i - NN] = 0;
    }
}

// ---------------- dispatch 2: UNFUSED histogram (+rank), 8 edges/thread -------
// Latency-bound phase gets the whole machine's wave slots + 8-deep atomic ILP.
// atomicAdd return = per-edge rank within node -> rank_buf (for atomic-free fill).
__global__ __launch_bounds__(256)
void k_hist(const int* __restrict__ ei0, const int* __restrict__ ei1,
            int* deg0, int* deg1,
            int* __restrict__ rank0, int* __restrict__ rank1) {
    int lvl = blockIdx.y;
    const int* col = (lvl ? ei1 : ei0) + NE;
    int* deg = lvl ? deg1 : deg0;
    int* rank = lvl ? rank1 : rank0;
    int i0 = (blockIdx.x * 256 + threadIdx.x) * 8;
    if (i0 >= NE) return;   // NE % 8 == 0 -> full octets only
    int4 ca = *(const int4*)(col + i0);
    int4 cb = *(const int4*)(col + i0 + 4);
    int4 ra, rb;
    ra.x = atomicAdd(&deg[ca.x], 1);
    ra.y = atomicAdd(&deg[ca.y], 1);
    ra.z = atomicAdd(&deg[ca.z], 1);
    ra.w = atomicAdd(&deg[ca.w], 1);
    rb.x = atomicAdd(&deg[cb.x], 1);
    rb.y = atomicAdd(&deg[cb.y], 1);
    rb.z = atomicAdd(&deg[cb.z], 1);
    rb.w = atomicAdd(&deg[cb.w], 1);
    *(int4*)(rank + i0) = ra;
    *(int4*)(rank + i0 + 4) = rb;
}

// ---------------- dispatch 3 (kA): prepx + weight-prep (streaming only) -------
// prepx: 8 elems/thread, vectorized
// slot y (0..5), Wt[n*256 + k]:
//   y<2 : nodeLin y   -> src[k*128+n], k<226, else 0
//   y>=2: layer y-2   -> k<128: lin1[k*128+n]; k>=128: lin2[(k-128)*128+n]
__global__ __launch_bounds__(256)
void kA(const void* x, const void* pe, unsigned short* __restrict__ xcat,
        const void* n1, const void* n2,
        const void* l11, const void* l21, const void* l12, const void* l22,
        const void* l13, const void* l23, const void* l14, const void* l24,
        unsigned short* __restrict__ wt, const int* __restrict__ dflag) {
    int b = blockIdx.x;
    int t = threadIdx.x;
    if (b < PREPXB) {
        int isbf = dflag[0];
        int id0 = b * 2048 + t * 8;
        int row = id0 >> 8, c0 = id0 & 255;   // c0 is a multiple of 8
        union { unsigned short u[8]; short8 v; } ob;
        if (c0 < DD) {
            // 8 consecutive x columns
            if (isbf) {
                ob.v = *(const short8*)((const unsigned short*)x + row * DD + c0);
            } else {
                float f[8];
                __builtin_memcpy(f, (const float*)x + row * DD + c0, 32);
#pragma unroll
                for (int j = 0; j < 8; j++) ob.u[j] = f_to_bfbits(f[j]);
            }
        } else if (c0 + 8 <= KPE) {
            // 8 consecutive pe columns (c0 = 128..216)
            int off = row * PEW + (c0 - DD);
            if (isbf) {
                unsigned short tmp[8];
                __builtin_memcpy(tmp, (const unsigned short*)pe + off, 16);
#pragma unroll
                for (int j = 0; j < 8; j++) ob.u[j] = tmp[j];
            } else {
                float f[8];
                __builtin_memcpy(f, (const float*)pe + off, 32);
#pragma unroll
                for (int j = 0; j < 8; j++) ob.u[j] = f_to_bfbits(f[j]);
            }
        } else {
            // mixed tail (c0 = 224) or pure zero pad (c0 = 232/240/248)
#pragma unroll
            for (int j = 0; j < 8; j++) {
                int c = c0 + j;
                float v = 0.f;
                if (c < KPE) v = ldf(pe, row * PEW + (c - DD), isbf);
                ob.u[j] = f_to_bfbits(v);
            }
        }
        *(short8*)(xcat + id0) = ob.v;
    } else {
        int b3 = b - PREPXB;
        int y = b3 >> 3, bx = b3 & 7;
        int kt = bx >> 1, nt = bx & 1;
        __shared__ float tile[64][65];
        int cc = t & 63, rr = t >> 6;
        int k0 = kt * 64, n0 = nt * 64;
        int isbf = dflag[0];
        const void* sA;   // source for k<128
        const void* sB;   // source for k>=128
        if (y == 0)      { sA = n1;  sB = n1; }
        else if (y == 1) { sA = n2;  sB = n2; }
        else if (y == 2) { sA = l11; sB = l21; }
        else if (y == 3) { sA = l12; sB = l22; }
        else if (y == 4) { sA = l13; sB = l23; }
        else             { sA = l14; sB = l24; }
#pragma unroll
        for (int i = 0; i < 16; i++) {
            int k = k0 + rr + i * 4;
            float v = 0.f;
            if (y < 2) {
                if (k < KPE) v = ldf(sA, k * DD + n0 + cc, isbf);
            } else {
                v = (k < 128) ? ldf(sA, k * DD + n0 + cc, isbf)
                              : ldf(sB, (k - 128) * DD + n0 + cc, isbf);
            }
            tile[rr + i * 4][cc] = v;
        }
        __syncthreads();
        unsigned short* w = wt + y * WSLOT;
#pragma unroll
        for (int i = 0; i < 16; i++) {
            int nn = rr + i * 4;
            w[(n0 + nn) * 256 + k0 + cc] = f_to_bfbits(tile[cc][nn]);
        }
    }
}

// ---------------- parallel scan (deg = real edges; dis = rsqrt(deg+1)) -----------
__global__ void k_scan1(const int* __restrict__ deg0, const int* __restrict__ deg1,
                        float* __restrict__ dis0, float* __restrict__ dis1,
                        int* __restrict__ bsum, int n) {
    int l = blockIdx.y;
    const int* deg = l ? deg1 : deg0;
    float* dis = l ? dis1 : dis0;
    int t = threadIdx.x;
    int base = blockIdx.x * 1024 + t * 4;
    int d[4] = {0, 0, 0, 0};
    if (base + 3 < n) {
        int4 q = *(const int4*)(deg + base);
        d[0] = q.x; d[1] = q.y; d[2] = q.z; d[3] = q.w;
    } else {
#pragma unroll
        for (int j = 0; j < 4; j++) if (base + j < n) d[j] = deg[base + j];
    }
#pragma unroll
    for (int j = 0; j < 4; j++)
        if (base + j < n) dis[base + j] = rsqrtf((float)(d[j] + 1));
    int s = d[0] + d[1] + d[2] + d[3];
#pragma unroll
    for (int off = 32; off >= 1; off >>= 1) s += __shfl_down(s, off, 64);
    __shared__ int ws[4];
    if ((t & 63) == 0) ws[t >> 6] = s;
    __syncthreads();
    if (t == 0) bsum[l * 64 + blockIdx.x] = ws[0] + ws[1] + ws[2] + ws[3];
}

__global__ void k_scan2(const int* __restrict__ bsum, int* __restrict__ boff) {
    int lane = threadIdx.x & 63;
    int l = threadIdx.x >> 6;
    int v = (lane < NB) ? bsum[l * 64 + lane] : 0;
    int s = v;
#pragma unroll
    for (int off = 1; off < 64; off <<= 1) {
        int u = __shfl_up(s, off, 64);
        if (lane >= off) s += u;
    }
    boff[l * 64 + lane] = s - v;   // exclusive
}

__global__ void k_scan3(const int* __restrict__ deg0, const int* __restrict__ deg1,
                        const int* __restrict__ boff,
                        int* __restrict__ cur0, int* __restrict__ cur1, int n) {
    int l = blockIdx.y;
    const int* deg = l ? deg1 : deg0;
    int* cur = l ? cur1 : cur0;
    int t = threadIdx.x;
    int base = blockIdx.x * 1024 + t * 4;
    int d[4] = {0, 0, 0, 0};
    if (base + 3 < n) {
        int4 q = *(const int4*)(deg + base);
        d[0] = q.x; d[1] = q.y; d[2] = q.z; d[3] = q.w;
    } else {
#pragma unroll
        for (int j = 0; j < 4; j++) if (base + j < n) d[j] = deg[base + j];
    }
    int s = d[0] + d[1] + d[2] + d[3];
    __shared__ int sc[256];
    sc[t] = s;
    __syncthreads();
    for (int off = 1; off < 256; off <<= 1) {
        int v = (t >= off) ? sc[t - off] : 0;
        __syncthreads();
        sc[t] += v;
        __syncthreads();
    }
    int p = boff[l * 64 + blockIdx.x] + sc[t] - s;   // exclusive prefix
#pragma unroll
    for (int j = 0; j < 4; j++) {
        if (base + j < n) { cur[base + j] = p; p += d[j]; }
    }
}

// ---- fill: 16B records {src, w1, w2, 0}, ATOMIC-FREE via precomputed ranks ----
// position = cur_start[col] + rank[i]; 4 edges/thread, vectorized loads.
// Plain stores (records must stay L2-resident for k_aggd's tile reads).
__global__ __launch_bounds__(256)
void k_fill(const int* __restrict__ ei0, const void* __restrict__ ea0,
            const float* __restrict__ dis0, const int* __restrict__ cur0,
            const int* __restrict__ rank0, int4* __restrict__ edges0,
            const int* __restrict__ ei1, const void* __restrict__ ea1,
            const float* __restrict__ dis1, const int* __restrict__ cur1,
            const int* __restrict__ rank1, int4* __restrict__ edges1,
            const int* __restrict__ dflag) {
    int lvl = blockIdx.y;
    const int* row = lvl ? ei1 : ei0;
    const int* col = row + NE;
    const void* attr = lvl ? ea1 : ea0;
    const float* dis = lvl ? dis1 : dis0;
    const int* cur = lvl ? cur1 : cur0;
    const int* rank = lvl ? rank1 : rank0;
    int4* edges = lvl ? edges1 : edges0;
    int i0 = (blockIdx.x * 256 + threadIdx.x) * 4;
    if (i0 >= NE) return;   // NE % 4 == 0 -> full quads only
    int4 rr = *(const int4*)(row + i0);
    int4 cc = *(const int4*)(col + i0);
    int4 rk = *(const int4*)(rank + i0);
    int isbf = dflag[0];
    float a[4];
    if (isbf) {
        unsigned short tmp[4];
        __builtin_memcpy(tmp, (const unsigned short*)attr + i0, 8);
#pragma unroll
        for (int j = 0; j < 4; j++) a[j] = bfbits_to_f(tmp[j]);
    } else {
        __builtin_memcpy(a, (const float*)attr + i0, 16);
    }
    int rv[4] = {rr.x, rr.y, rr.z, rr.w};
    int cv[4] = {cc.x, cc.y, cc.z, cc.w};
    int kv[4] = {rk.x, rk.y, rk.z, rk.w};
#pragma unroll
    for (int j = 0; j < 4; j++) {
        int p = cur[cv[j]] + kv[j];
        float w2 = (a[j] > 0.f) ? fminf(rsqrtf(a[j]), 1.f) : 0.f;
        int4 rec;
        rec.x = rv[j];
        rec.y = f_as_i(dis[rv[j]] * dis[cv[j]]);
        rec.z = f_as_i(w2);
        rec.w = 0;
        edges[p] = rec;
    }
}

// ---------------- GEMM core: 64x128 tile, K=256, bf16 MFMA ----------------
__device__ __forceinline__ void gemm_core(const unsigned short* __restrict__ A,
                                          const unsigned short* __restrict__ wt,
                                          int row0, float4v acc[8]) {
    __shared__ short A_s[64 * 72];
    __shared__ short B_s[128 * 72];
    int tid = threadIdx.x;
    int lane = tid & 63, w = tid >> 6;
    int m = lane & 15, quad = lane >> 4;
#pragma unroll
    for (int t = 0; t < 8; t++) acc[t] = (float4v){0.f, 0.f, 0.f, 0.f};
    for (int c = 0; c < 4; c++) {
#pragma unroll
        for (int i = 0; i < 2; i++) {
            int e = (i * 256 + tid) * 8;
            int r = e >> 6, cc = e & 63;
            int rr = row0 + r;
            short8 v = {0, 0, 0, 0, 0, 0, 0, 0};
            if (rr < NN) v = *(const short8*)(A + rr * 256 + c * 64 + cc);
            *(short8*)&A_s[r * 72 + cc] = v;
        }
#pragma unroll
        for (int i = 0; i < 4; i++) {
            int e = (i * 256 + tid) * 8;
            int nr = e >> 6, kk = e & 63;
            *(short8*)&B_s[nr * 72 + kk] = *(const short8*)(wt + nr * 256 + c * 64 + kk);
        }
        __syncthreads();
#pragma unroll
        for (int c2 = 0; c2 < 2; c2++) {
            short8 a = *(short8*)&A_s[(w * 16 + m) * 72 + c2 * 32 + quad * 8];
#pragma unroll
            for (int t = 0; t < 8; t++) {
                short8 b = *(short8*)&B_s[(t * 16 + m) * 72 + c2 * 32 + quad * 8];
                acc[t] = __builtin_amdgcn_mfma_f32_16x16x32_bf16(a, b, acc[t], 0, 0, 0);
            }
        }
        __syncthreads();
    }
}

// ---------------- PE GEMM: xpe{1,2} = xcat @ nodeLin{1,2} (plain write) ----------
__global__ __launch_bounds__(256)
void k_gemm_pe(const unsigned short* __restrict__ xcat,
               const unsigned short* __restrict__ wt,
               unsigned short* __restrict__ out0, unsigned short* __restrict__ out1) {
    float4v acc[8];
    gemm_core(xcat, wt + (blockIdx.y ? WSLOT : 0), blockIdx.x * 64, acc);
    unsigned short* out = blockIdx.y ? out1 : out0;
    int lane = threadIdx.x & 63, w = threadIdx.x >> 6;
    int m = lane & 15, quad = lane >> 4;
    int row0 = blockIdx.x * 64;
#pragma unroll
    for (int t = 0; t < 8; t++)
#pragma unroll
        for (int r = 0; r < 4; r++) {
            int row = row0 + w * 16 + quad * 4 + r;
            if (row < NN) out[row * DD + t * 16 + m] = f_to_bfbits(acc[t][r]);
        }
}

// ---------------- layer GEMM: out = epilogue(acat @ Wcat) ----------------
// mode 1: relu -> bf16 out
// mode 2: 0.5*relu + 0.5*blend -> bf16 out
// mode 3: 0.5*relu + 0.5*blend -> outFinal (bf16 or f32 per dflag)
__global__ __launch_bounds__(256)
void k_gemmL(const unsigned short* __restrict__ acat,
             const unsigned short* __restrict__ wt,
             const unsigned short* __restrict__ blendIn,
             unsigned short* __restrict__ out, void* __restrict__ outFinal,
             const int* __restrict__ dflag, int mode) {
    float4v acc[8];
    gemm_core(acat, wt, blockIdx.x * 64, acc);
    int lane = threadIdx.x & 63, w = threadIdx.x >> 6;
    int m = lane & 15, quad = lane >> 4;
    int row0 = blockIdx.x * 64;
    int isbf = (mode == 3) ? dflag[0] : 1;
#pragma unroll
    for (int t = 0; t < 8; t++) {
        int colc = t * 16 + m;
#pragma unroll
        for (int r = 0; r < 4; r++) {
            int row = row0 + w * 16 + quad * 4 + r;
            if (row >= NN) continue;
            float v = fmaxf(acc[t][r], 0.f);
            if (mode >= 2)
                v = 0.5f * v + 0.5f * bfbits_to_f(blendIn[row * DD + colc]);
            if (mode == 3 && !isbf)
                ((float*)outFinal)[row * DD + colc] = v;
            else if (mode == 3)
                ((unsigned short*)outFinal)[row * DD + colc] = f_to_bfbits(v);
            else
                out[row * DD + colc] = f_to_bfbits(v);
        }
    }
}

// ---------------- dual-level aggregation over X (a1|a2 -> acat[N,256]) ----------
// 1 wave per node. LANE-TILED record read: lane i loads record (start+i)
// (one coalesced 1KB load covers up to 64 edges), then each edge's
// {src,w1,w2} is broadcast via __shfl — no per-edge record memory latency,
// no serial tail (OOB edges get zeroed weights, gathers clamped to a valid
// row). Gathers issued 8-at-a-time for MLP. Analytic self-loop.
// cur[] holds START offsets.
__global__ __launch_bounds__(256)
void k_aggd(const int4* __restrict__ edges0, const int* __restrict__ cur0,
            const int* __restrict__ deg0, const float* __restrict__ dis0,
            const unsigned short* __restrict__ X0, unsigned short* __restrict__ acat0,
            const int4* __restrict__ edges1, const int* __restrict__ cur1,
            const int* __restrict__ deg1, const float* __restrict__ dis1,
            const unsigned short* __restrict__ X1, unsigned short* __restrict__ acat1) {
    int b = blockIdx.x;
    int lvl = b >= AGGB;
    const int4* edges = lvl ? edges1 : edges0;
    const int* cur = lvl ? cur1 : cur0;
    const int* deg = lvl ? deg1 : deg0;
    const float* dis = lvl ? dis1 : dis0;
    const unsigned short* X = lvl ? X1 : X0;
    unsigned short* acat = lvl ? acat1 : acat0;
    int wave = ((b - (lvl ? AGGB : 0)) * 256 + threadIdx.x) >> 6;
    int lane = threadIdx.x & 63;
    if (wave >= NN) return;
    int start = cur[wave];
    int d = deg[wave];
    int end = start + d;
    float dn = dis[wave];
    int c0 = lane * 2;
    float a1l0 = 0.f, a1h0 = 0.f, a2l0 = 0.f, a2h0 = 0.f;
    float a1l1 = 0.f, a1h1 = 0.f, a2l1 = 0.f, a2h1 = 0.f;
    int s = start;
    while (s < end) {
        int take = end - s;
        if (take > 64) take = 64;
        int li = s + lane;
        int4 rec = edges[(li < end) ? li : (end - 1)];
        for (int j0 = 0; j0 < take; j0 += 8) {
            int   src[8];
            float w1[8], w2[8];
#pragma unroll
            for (int jj = 0; jj < 8; jj++) {
                int j = j0 + jj;
                src[jj] = __shfl(rec.x, j, 64);
                float ww1 = bits_to_f((unsigned int)__shfl(rec.y, j, 64));
                float ww2 = bits_to_f((unsigned int)__shfl(rec.z, j, 64));
                int ok = j < take;
                w1[jj] = ok ? ww1 : 0.f;
                w2[jj] = ok ? ww2 : 0.f;
            }
            unsigned int q[8];
#pragma unroll
            for (int jj = 0; jj < 8; jj++)
                q[jj] = *(const unsigned int*)(X + src[jj] * DD + c0);
#pragma unroll
            for (int jj = 0; jj < 8; jj++) {
                float xl = bits_to_f(q[jj] << 16);
                float xh = bits_to_f(q[jj] & 0xFFFF0000u);
                if (jj & 1) {
                    a1l1 = fmaf(w1[jj], xl, a1l1); a1h1 = fmaf(w1[jj], xh, a1h1);
                    a2l1 = fmaf(w2[jj], xl, a2l1); a2h1 = fmaf(w2[jj], xh, a2h1);
                } else {
                    a1l0 = fmaf(w1[jj], xl, a1l0); a1h0 = fmaf(w1[jj], xh, a1h0);
                    a2l0 = fmaf(w2[jj], xl, a2l0); a2h0 = fmaf(w2[jj], xh, a2h0);
                }
            }
        }
        s += take;
    }
    // analytic self loop
    {
        unsigned int q = *(const unsigned int*)(X + wave * DD + c0);
        float xl = bits_to_f(q << 16), xh = bits_to_f(q & 0xFFFF0000u);
        float dn2 = dn * dn;
        a1l0 = fmaf(dn2, xl, a1l0); a1h0 = fmaf(dn2, xh, a1h0);
        a2l0 += xl; a2h0 += xh;
    }
    float s1l = a1l0 + a1l1, s1h = a1h0 + a1h1;
    float s2l = a2l0 + a2l1, s2h = a2h0 + a2h1;
    unsigned int pk1 = (unsigned int)f_to_bfbits(s1l) |
                       ((unsigned int)f_to_bfbits(s1h) << 16);
    unsigned int pk2 = (unsigned int)f_to_bfbits(s2l) |
                       ((unsigned int)f_to_bfbits(s2h) << 16);
    *(unsigned int*)(acat + wave * 256 + c0) = pk1;
    *(unsigned int*)(acat + wave * 256 + 128 + c0) = pk2;
}

// ---------------- Launch ----------------

#define PADUP(x) (((x) + 255) & ~(size_t)255)

extern "C" void kernel_launch(void* const* d_in, const int* in_sizes, int n_in,
                              void* d_out, int out_size, void* d_ws, size_t ws_size,
                              hipStream_t stream) {
    (void)in_sizes; (void)n_in; (void)out_size; (void)ws_size;

    const void* x    = d_in[0];
    const void* d2an = d_in[1];
    const int*  ei0  = (const int*)d_in[2];
    const void* ea0  = d_in[3];
    const int*  ei1  = (const int*)d_in[4];
    const void* ea1  = d_in[5];

    char* p = (char*)d_ws;
    unsigned short* xpe1 = (unsigned short*)p; p += PADUP((size_t)NN * DD * 2);
    unsigned short* xpe2 = (unsigned short*)p; p += PADUP((size_t)NN * DD * 2);
    unsigned short* x0b  = (unsigned short*)p; p += PADUP((size_t)NN * DD * 2);
    unsigned short* xm   = (unsigned short*)p; p += PADUP((size_t)NN * DD * 2);
    unsigned short* xcat = (unsigned short*)p; p += PADUP((size_t)NN * 256 * 2);
    unsigned short* acat0 = xcat;              // xcat dead after PE GEMM
    unsigned short* acat1 = (unsigned short*)p; p += PADUP((size_t)NN * 256 * 2);
    unsigned short* wt   = (unsigned short*)p; p += PADUP((size_t)6 * WSLOT * 2);
    int*   deg0 = (int*)p;    p += PADUP((size_t)NN * 4);
    int*   cur0 = (int*)p;    p += PADUP((size_t)NN * 4);
    float* dis0 = (float*)p;  p += PADUP((size_t)NN * 4);
    int*   deg1 = (int*)p;    p += PADUP((size_t)NN * 4);
    int*   cur1 = (int*)p;    p += PADUP((size_t)NN * 4);
    float* dis1 = (float*)p;  p += PADUP((size_t)NN * 4);
    int4*  edges0 = (int4*)p; p += PADUP((size_t)NE * 16);
    int4*  edges1 = (int4*)p; p += PADUP((size_t)NE * 16);
    int*   bsum = (int*)p;    p += PADUP((size_t)128 * 4);
    int*   boff = (int*)p;    p += PADUP((size_t)128 * 4);
    int*   dflag = (int*)p;

    // rank buffers alias xpe1/xpe2: written by k_hist, consumed by k_fill,
    // both strictly before k_gemm_pe writes xpe1/xpe2 (stream-ordered).
    int* rank0 = (int*)xpe1;   // NE*4 = 6.4MB <= NN*DD*2 = 12.8MB
    int* rank1 = (int*)xpe2;

    // 1. detect + zero degrees
    k_detect0<<<392, 256, 0, stream>>>((const unsigned int*)x, dflag, (float*)d_out,
                                       deg0, deg1);
    // 2. histogram(+rank) — UNFUSED, full-machine occupancy, 8-deep atomic ILP
    k_hist<<<dim3(HIST8B, 2), 256, 0, stream>>>(ei0, ei1, deg0, deg1, rank0, rank1);
    // 3. prepx + weight prep (pure streaming)
    kA<<<PREPXB + PREPB, 256, 0, stream>>>(
        x, d2an, xcat,
        d_in[6], d_in[7], d_in[8], d_in[9], d_in[10], d_in[11], d_in[12],
        d_in[13], d_in[14], d_in[15], wt, dflag);
    // 4-6. parallel scan
    k_scan1<<<dim3(NB, 2), 256, 0, stream>>>(deg0, deg1, dis0, dis1, bsum, NN);
    k_scan2<<<1, 128, 0, stream>>>(bsum, boff);
    k_scan3<<<dim3(NB, 2), 256, 0, stream>>>(deg0, deg1, boff, cur0, cur1, NN);
    // 7. edge fill — atomic-free via ranks
    k_fill<<<dim3(FILLB, 2), 256, 0, stream>>>(ei0, ea0, dis0, cur0, rank0, edges0,
                                               ei1, ea1, dis1, cur1, rank1, edges1,
                                               dflag);
    // 8. PE GEMM: xpe1/xpe2 = xcat @ nodeLin{1,2}   (overwrites rank buffers; ok)
    k_gemm_pe<<<dim3(GX, 2), 256, 0, stream>>>(xcat, wt, xpe1, xpe2);
    // 9. dual agg round 1: acat0 = agg0(xpe1), acat1 = agg1(xpe2)
    k_aggd<<<2 * AGGB, 256, 0, stream>>>(edges0, cur0, deg0, dis0, xpe1, acat0,
                                         edges1, cur1, deg1, dis1, xpe2, acat1);
    // 10. x0 = relu(acat0 @ Wcat_1) -> x0b
    k_gemmL<<<GX, 256, 0, stream>>>(acat0, wt + 2 * WSLOT,
                                    (const unsigned short*)0, x0b, (void*)0,
                                    dflag, 1);
    // 11. xm = 0.5*relu(acat1 @ Wcat_2) + 0.5*x0b
    k_gemmL<<<GX, 256, 0, stream>>>(acat1, wt + 3 * WSLOT, x0b, xm, (void*)0,
                                    dflag, 2);
    // 12. dual agg round 2: acat0 = agg0(xm), acat1 = agg1(xm)
    k_aggd<<<2 * AGGB, 256, 0, stream>>>(edges0, cur0, deg0, dis0, xm, acat0,
                                         edges1, cur1, deg1, dis1, xm, acat1);
    // 13. x0 = relu(acat0 @ Wcat_3) -> x0b
    k_gemmL<<<GX, 256, 0, stream>>>(acat0, wt + 4 * WSLOT,
                                    (const unsigned short*)0, x0b, (void*)0,
                                    dflag, 1);
    // 14. out = 0.5*relu(acat1 @ Wcat_4) + 0.5*x0b  (bf16/f32 per dflag)
    k_gemmL<<<GX, 256, 0, stream>>>(acat1, wt + 5 * WSLOT, x0b,
                                    (unsigned short*)0, d_out, dflag, 3);
}

// Round 8
// 481.421 us; speedup vs baseline: 1.0256x; 1.0256x over previous
//
#include <hip/hip_runtime.h>

#define NN 50000
#define NE 800000
#define DD 128
#define PEW 98
#define KPE 226
#define WSLOT 32768   // bf16 elements per weight slot (128 n x 256 k)
#define NB 49         // scan blocks per level: ceil(NN/1024)
#define GX 782        // ceil(NN/64) gemm row-tiles
#define HIST8B 391    // ceil(NE/(256*8)) hist blocks per level (8 edges/thread)
#define FILLB 782     // ceil(NE/(256*4)) fill blocks per level
#define PREPXB 6250   // NN*256/(256*8) prepx blocks (8 elems/thread)
#define PREPB 48      // 6 slots x 8 tile-blocks
#define AGGB 12500    // ceil(NN/4): 1 wave per node, 4 nodes/block

typedef __attribute__((ext_vector_type(8))) short short8;
typedef __attribute__((ext_vector_type(4))) float float4v;
typedef __attribute__((ext_vector_type(2))) float float2v;

// Kept so anything that looks up the original kernel name still finds a symbol.
__global__ void GraphTrajSTEncoder_67362267070834_kernel() {}

// ---------------- dtype helpers ----------------

__device__ __forceinline__ float bfbits_to_f(unsigned int u16) {
    unsigned int v = u16 << 16;
    float f;
    __builtin_memcpy(&f, &v, 4);
    return f;
}

__device__ __forceinline__ float bits_to_f(unsigned int v) {
    float f;
    __builtin_memcpy(&f, &v, 4);
    return f;
}

__device__ __forceinline__ int f_as_i(float f) {
    int i;
    __builtin_memcpy(&i, &f, 4);
    return i;
}

__device__ __forceinline__ unsigned short f_to_bfbits(float f) {
    unsigned int b;
    __builtin_memcpy(&b, &f, 4);
    unsigned int r = b + 0x7FFFu + ((b >> 16) & 1u);   // round to nearest even
    return (unsigned short)(r >> 16);
}

__device__ __forceinline__ float ldf(const void* p, int i, int isbf) {
    if (isbf) return bfbits_to_f(((const unsigned short*)p)[i]);
    return ((const float*)p)[i];
}

// ---------------- dispatch 1: dtype detect + zero degree arrays ----------------
__global__ __launch_bounds__(256)
void k_detect0(const unsigned int* xw, int* flag, float* dout_sentinel,
               int* deg0, int* deg1) {
    if (blockIdx.x == 0) {
        __shared__ int cnt;
        if (threadIdx.x == 0) cnt = 0;
        __syncthreads();
        unsigned int w = xw[threadIdx.x];
        unsigned int e = (w >> 7) & 0xFFu;
        atomicAdd(&cnt, (e >= 100u && e <= 150u) ? 1 : 0);
        __syncthreads();
        if (threadIdx.x == 0) {
            flag[0] = (cnt >= 128) ? 1 : 0;
            dout_sentinel[0] = 1.0e6f;
        }
    } else {
        int i = (blockIdx.x - 1) * 256 + threadIdx.x;
        if (i < NN) deg0[i] = 0;
        else if (i < 2 * NN) deg1[i - NN] = 0;
    }
}

// ---------------- dispatch 2: UNFUSED histogram (+rank), 8 edges/thread -------
// Latency-bound phase gets the whole machine's wave slots + 8-deep atomic ILP.
// atomicAdd return = per-edge rank within node -> rank_buf (for atomic-free fill).
__global__ __launch_bounds__(256)
void k_hist(const int* __restrict__ ei0, const int* __restrict__ ei1,
            int* deg0, int* deg1,
            int* __restrict__ rank0, int* __restrict__ rank1) {
    int lvl = blockIdx.y;
    const int* col = (lvl ? ei1 : ei0) + NE;
    int* deg = lvl ? deg1 : deg0;
    int* rank = lvl ? rank1 : rank0;
    int i0 = (blockIdx.x * 256 + threadIdx.x) * 8;
    if (i0 >= NE) return;   // NE % 8 == 0 -> full octets only
    int4 ca = *(const int4*)(col + i0);
    int4 cb = *(const int4*)(col + i0 + 4);
    int4 ra, rb;
    ra.x = atomicAdd(&deg[ca.x], 1);
    ra.y = atomicAdd(&deg[ca.y], 1);
    ra.z = atomicAdd(&deg[ca.z], 1);
    ra.w = atomicAdd(&deg[ca.w], 1);
    rb.x = atomicAdd(&deg[cb.x], 1);
    rb.y = atomicAdd(&deg[cb.y], 1);
    rb.z = atomicAdd(&deg[cb.z], 1);
    rb.w = atomicAdd(&deg[cb.w], 1);
    *(int4*)(rank + i0) = ra;
    *(int4*)(rank + i0 + 4) = rb;
}

// ---------------- dispatch 3 (kA): prepx + weight-prep (streaming only) -------
// prepx: 8 elems/thread, vectorized
// slot y (0..5), Wt[n*256 + k]:
//   y<2 : nodeLin y   -> src[k*128+n], k<226, else 0
//   y>=2: layer y-2   -> k<128: lin1[k*128+n]; k>=128: lin2[(k-128)*128+n]
__global__ __launch_bounds__(256)
void kA(const void* x, const void* pe, unsigned short* __restrict__ xcat,
        const void* n1, const void* n2,
        const void* l11, const void* l21, const void* l12, const void* l22,
        const void* l13, const void* l23, const void* l14, const void* l24,
        unsigned short* __restrict__ wt, const int* __restrict__ dflag) {
    int b = blockIdx.x;
    int t = threadIdx.x;
    if (b < PREPXB) {
        int isbf = dflag[0];
        int id0 = b * 2048 + t * 8;
        int row = id0 >> 8, c0 = id0 & 255;   // c0 is a multiple of 8
        union { unsigned short u[8]; short8 v; } ob;
        if (c0 < DD) {
            // 8 consecutive x columns
            if (isbf) {
                ob.v = *(const short8*)((const unsigned short*)x + row * DD + c0);
            } else {
                float f[8];
                __builtin_memcpy(f, (const float*)x + row * DD + c0, 32);
#pragma unroll
                for (int j = 0; j < 8; j++) ob.u[j] = f_to_bfbits(f[j]);
            }
        } else if (c0 + 8 <= KPE) {
            // 8 consecutive pe columns (c0 = 128..216)
            int off = row * PEW + (c0 - DD);
            if (isbf) {
                unsigned short tmp[8];
                __builtin_memcpy(tmp, (const unsigned short*)pe + off, 16);
#pragma unroll
                for (int j = 0; j < 8; j++) ob.u[j] = tmp[j];
            } else {
                float f[8];
                __builtin_memcpy(f, (const float*)pe + off, 32);
#pragma unroll
                for (int j = 0; j < 8; j++) ob.u[j] = f_to_bfbits(f[j]);
            }
        } else {
            // mixed tail (c0 = 224) or pure zero pad (c0 = 232/240/248)
#pragma unroll
            for (int j = 0; j < 8; j++) {
                int c = c0 + j;
                float v = 0.f;
                if (c < KPE) v = ldf(pe, row * PEW + (c - DD), isbf);
                ob.u[j] = f_to_bfbits(v);
            }
        }
        *(short8*)(xcat + id0) = ob.v;
    } else {
        int b3 = b - PREPXB;
        int y = b3 >> 3, bx = b3 & 7;
        int kt = bx >> 1, nt = bx & 1;
        __shared__ float tile[64][65];
        int cc = t & 63, rr = t >> 6;
        int k0 = kt * 64, n0 = nt * 64;
        int isbf = dflag[0];
        const void* sA;   // source for k<128
        const void* sB;   // source for k>=128
        if (y == 0)      { sA = n1;  sB = n1; }
        else if (y == 1) { sA = n2;  sB = n2; }
        else if (y == 2) { sA = l11; sB = l21; }
        else if (y == 3) { sA = l12; sB = l22; }
        else if (y == 4) { sA = l13; sB = l23; }
        else             { sA = l14; sB = l24; }
#pragma unroll
        for (int i = 0; i < 16; i++) {
            int k = k0 + rr + i * 4;
            float v = 0.f;
            if (y < 2) {
                if (k < KPE) v = ldf(sA, k * DD + n0 + cc, isbf);
            } else {
                v = (k < 128) ? ldf(sA, k * DD + n0 + cc, isbf)
                              : ldf(sB, (k - 128) * DD + n0 + cc, isbf);
            }
            tile[rr + i * 4][cc] = v;
        }
        __syncthreads();
        unsigned short* w = wt + y * WSLOT;
#pragma unroll
        for (int i = 0; i < 16; i++) {
            int nn = rr + i * 4;
            w[(n0 + nn) * 256 + k0 + cc] = f_to_bfbits(tile[cc][nn]);
        }
    }
}

// ---------------- parallel scan (deg = real edges; dis = rsqrt(deg+1)) -----------
__global__ void k_scan1(const int* __restrict__ deg0, const int* __restrict__ deg1,
                        float* __restrict__ dis0, float* __restrict__ dis1,
                        int* __restrict__ bsum, int n) {
    int l = blockIdx.y;
    const int* deg = l ? deg1 : deg0;
    float* dis = l ? dis1 : dis0;
    int t = threadIdx.x;
    int base = blockIdx.x * 1024 + t * 4;
    int d[4] = {0, 0, 0, 0};
    if (base + 3 < n) {
        int4 q = *(const int4*)(deg + base);
        d[0] = q.x; d[1] = q.y; d[2] = q.z; d[3] = q.w;
    } else {
#pragma unroll
        for (int j = 0; j < 4; j++) if (base + j < n) d[j] = deg[base + j];
    }
#pragma unroll
    for (int j = 0; j < 4; j++)
        if (base + j < n) dis[base + j] = rsqrtf((float)(d[j] + 1));
    int s = d[0] + d[1] + d[2] + d[3];
#pragma unroll
    for (int off = 32; off >= 1; off >>= 1) s += __shfl_down(s, off, 64);
    __shared__ int ws[4];
    if ((t & 63) == 0) ws[t >> 6] = s;
    __syncthreads();
    if (t == 0) bsum[l * 64 + blockIdx.x] = ws[0] + ws[1] + ws[2] + ws[3];
}

__global__ void k_scan2(const int* __restrict__ bsum, int* __restrict__ boff) {
    int lane = threadIdx.x & 63;
    int l = threadIdx.x >> 6;
    int v = (lane < NB) ? bsum[l * 64 + lane] : 0;
    int s = v;
#pragma unroll
    for (int off = 1; off < 64; off <<= 1) {
        int u = __shfl_up(s, off, 64);
        if (lane >= off) s += u;
    }
    boff[l * 64 + lane] = s - v;   // exclusive
}

__global__ void k_scan3(const int* __restrict__ deg0, const int* __restrict__ deg1,
                        const int* __restrict__ boff,
                        int* __restrict__ cur0, int* __restrict__ cur1, int n) {
    int l = blockIdx.y;
    const int* deg = l ? deg1 : deg0;
    int* cur = l ? cur1 : cur0;
    int t = threadIdx.x;
    int base = blockIdx.x * 1024 + t * 4;
    int d[4] = {0, 0, 0, 0};
    if (base + 3 < n) {
        int4 q = *(const int4*)(deg + base);
        d[0] = q.x; d[1] = q.y; d[2] = q.z; d[3] = q.w;
    } else {
#pragma unroll
        for (int j = 0; j < 4; j++) if (base + j < n) d[j] = deg[base + j];
    }
    int s = d[0] + d[1] + d[2] + d[3];
    __shared__ int sc[256];
    sc[t] = s;
    __syncthreads();
    for (int off = 1; off < 256; off <<= 1) {
        int v = (t >= off) ? sc[t - off] : 0;
        __syncthreads();
        sc[t] += v;
        __syncthreads();
    }
    int p = boff[l * 64 + blockIdx.x] + sc[t] - s;   // exclusive prefix
#pragma unroll
    for (int j = 0; j < 4; j++) {
        if (base + j < n) { cur[base + j] = p; p += d[j]; }
    }
}

// ---- fill: 16B records {src, w1, w2, 0}, ATOMIC-FREE via precomputed ranks ----
// position = cur_start[col] + rank[i]; 4 edges/thread, vectorized loads.
// Plain stores (records must stay L2-resident for k_aggd's tile reads).
__global__ __launch_bounds__(256)
void k_fill(const int* __restrict__ ei0, const void* __restrict__ ea0,
            const float* __restrict__ dis0, const int* __restrict__ cur0,
            const int* __restrict__ rank0, int4* __restrict__ edges0,
            const int* __restrict__ ei1, const void* __restrict__ ea1,
            const float* __restrict__ dis1, const int* __restrict__ cur1,
            const int* __restrict__ rank1, int4* __restrict__ edges1,
            const int* __restrict__ dflag) {
    int lvl = blockIdx.y;
    const int* row = lvl ? ei1 : ei0;
    const int* col = row + NE;
    const void* attr = lvl ? ea1 : ea0;
    const float* dis = lvl ? dis1 : dis0;
    const int* cur = lvl ? cur1 : cur0;
    const int* rank = lvl ? rank1 : rank0;
    int4* edges = lvl ? edges1 : edges0;
    int i0 = (blockIdx.x * 256 + threadIdx.x) * 4;
    if (i0 >= NE) return;   // NE % 4 == 0 -> full quads only
    int4 rr = *(const int4*)(row + i0);
    int4 cc = *(const int4*)(col + i0);
    int4 rk = *(const int4*)(rank + i0);
    int isbf = dflag[0];
    float a[4];
    if (isbf) {
        unsigned short tmp[4];
        __builtin_memcpy(tmp, (const unsigned short*)attr + i0, 8);
#pragma unroll
        for (int j = 0; j < 4; j++) a[j] = bfbits_to_f(tmp[j]);
    } else {
        __builtin_memcpy(a, (const float*)attr + i0, 16);
    }
    int rv[4] = {rr.x, rr.y, rr.z, rr.w};
    int cv[4] = {cc.x, cc.y, cc.z, cc.w};
    int kv[4] = {rk.x, rk.y, rk.z, rk.w};
#pragma unroll
    for (int j = 0; j < 4; j++) {
        int p = cur[cv[j]] + kv[j];
        float w2 = (a[j] > 0.f) ? fminf(rsqrtf(a[j]), 1.f) : 0.f;
        int4 rec;
        rec.x = rv[j];
        rec.y = f_as_i(dis[rv[j]] * dis[cv[j]]);
        rec.z = f_as_i(w2);
        rec.w = 0;
        edges[p] = rec;
    }
}

// ---------------- GEMM core: 64x128 tile, K=256, bf16 MFMA ----------------
__device__ __forceinline__ void gemm_core(const unsigned short* __restrict__ A,
                                          const unsigned short* __restrict__ wt,
                                          int row0, float4v acc[8]) {
    __shared__ short A_s[64 * 72];
    __shared__ short B_s[128 * 72];
    int tid = threadIdx.x;
    int lane = tid & 63, w = tid >> 6;
    int m = lane & 15, quad = lane >> 4;
#pragma unroll
    for (int t = 0; t < 8; t++) acc[t] = (float4v){0.f, 0.f, 0.f, 0.f};
    for (int c = 0; c < 4; c++) {
#pragma unroll
        for (int i = 0; i < 2; i++) {
            int e = (i * 256 + tid) * 8;
            int r = e >> 6, cc = e & 63;
            int rr = row0 + r;
            short8 v = {0, 0, 0, 0, 0, 0, 0, 0};
            if (rr < NN) v = *(const short8*)(A + rr * 256 + c * 64 + cc);
            *(short8*)&A_s[r * 72 + cc] = v;
        }
#pragma unroll
        for (int i = 0; i < 4; i++) {
            int e = (i * 256 + tid) * 8;
            int nr = e >> 6, kk = e & 63;
            *(short8*)&B_s[nr * 72 + kk] = *(const short8*)(wt + nr * 256 + c * 64 + kk);
        }
        __syncthreads();
#pragma unroll
        for (int c2 = 0; c2 < 2; c2++) {
            short8 a = *(short8*)&A_s[(w * 16 + m) * 72 + c2 * 32 + quad * 8];
#pragma unroll
            for (int t = 0; t < 8; t++) {
                short8 b = *(short8*)&B_s[(t * 16 + m) * 72 + c2 * 32 + quad * 8];
                acc[t] = __builtin_amdgcn_mfma_f32_16x16x32_bf16(a, b, acc[t], 0, 0, 0);
            }
        }
        __syncthreads();
    }
}

// ---------------- PE GEMM: xpe{1,2} = xcat @ nodeLin{1,2} (plain write) ----------
__global__ __launch_bounds__(256)
void k_gemm_pe(const unsigned short* __restrict__ xcat,
               const unsigned short* __restrict__ wt,
               unsigned short* __restrict__ out0, unsigned short* __restrict__ out1) {
    float4v acc[8];
    gemm_core(xcat, wt + (blockIdx.y ? WSLOT : 0), blockIdx.x * 64, acc);
    unsigned short* out = blockIdx.y ? out1 : out0;
    int lane = threadIdx.x & 63, w = threadIdx.x >> 6;
    int m = lane & 15, quad = lane >> 4;
    int row0 = blockIdx.x * 64;
#pragma unroll
    for (int t = 0; t < 8; t++)
#pragma unroll
        for (int r = 0; r < 4; r++) {
            int row = row0 + w * 16 + quad * 4 + r;
            if (row < NN) out[row * DD + t * 16 + m] = f_to_bfbits(acc[t][r]);
        }
}

// ---------------- layer GEMM: out = epilogue(acat @ Wcat) ----------------
// mode 1: relu -> bf16 out
// mode 2: 0.5*relu + 0.5*blend -> bf16 out
// mode 3: 0.5*relu + 0.5*blend -> outFinal (bf16 or f32 per dflag)
__global__ __launch_bounds__(256)
void k_gemmL(const unsigned short* __restrict__ acat,
             const unsigned short* __restrict__ wt,
             const unsigned short* __restrict__ blendIn,
             unsigned short* __restrict__ out, void* __restrict__ outFinal,
             const int* __restrict__ dflag, int mode) {
    float4v acc[8];
    gemm_core(acat, wt, blockIdx.x * 64, acc);
    int lane = threadIdx.x & 63, w = threadIdx.x >> 6;
    int m = lane & 15, quad = lane >> 4;
    int row0 = blockIdx.x * 64;
    int isbf = (mode == 3) ? dflag[0] : 1;
#pragma unroll
    for (int t = 0; t < 8; t++) {
        int colc = t * 16 + m;
#pragma unroll
        for (int r = 0; r < 4; r++) {
            int row = row0 + w * 16 + quad * 4 + r;
            if (row >= NN) continue;
            float v = fmaxf(acc[t][r], 0.f);
            if (mode >= 2)
                v = 0.5f * v + 0.5f * bfbits_to_f(blendIn[row * DD + colc]);
            if (mode == 3 && !isbf)
                ((float*)outFinal)[row * DD + colc] = v;
            else if (mode == 3)
                ((unsigned short*)outFinal)[row * DD + colc] = f_to_bfbits(v);
            else
                out[row * DD + colc] = f_to_bfbits(v);
        }
    }
}

// ---------------- dual-level aggregation over X (a1|a2 -> acat[N,256]) ----------
// 1 wave per node, PAIR-PROCESSED: lanes 0-31 handle edge j, lanes 32-63 edge
// j+1; each lane owns 4 columns (8B uint2 gather). Lane-tiled record read +
// __shfl broadcast with per-lane index (j+half). Packed float2 FMAs. Epilogue:
// single cross-half exchange (half0 keeps a1, half1 keeps a2), branch-free
// self-loop via per-half scale, one coalesced 8B store per lane.
// cur[] holds START offsets.
__global__ __launch_bounds__(256)
void k_aggd(const int4* __restrict__ edges0, const int* __restrict__ cur0,
            const int* __restrict__ deg0, const float* __restrict__ dis0,
            const unsigned short* __restrict__ X0, unsigned short* __restrict__ acat0,
            const int4* __restrict__ edges1, const int* __restrict__ cur1,
            const int* __restrict__ deg1, const float* __restrict__ dis1,
            const unsigned short* __restrict__ X1, unsigned short* __restrict__ acat1) {
    int b = blockIdx.x;
    int lvl = b >= AGGB;
    const int4* edges = lvl ? edges1 : edges0;
    const int* cur = lvl ? cur1 : cur0;
    const int* deg = lvl ? deg1 : deg0;
    const float* dis = lvl ? dis1 : dis0;
    const unsigned short* X = lvl ? X1 : X0;
    unsigned short* acat = lvl ? acat1 : acat0;
    int wave = ((b - (lvl ? AGGB : 0)) * 256 + threadIdx.x) >> 6;
    int lane = threadIdx.x & 63;
    if (wave >= NN) return;
    int half = lane >> 5;          // which edge of each pair this lane serves
    int sub = lane & 31;           // 32 lanes per edge-row
    int e0 = sub * 4;              // first of this lane's 4 bf16 columns
    int start = cur[wave];
    int d = deg[wave];
    int end = start + d;
    float dn = dis[wave];
    float2v a1lo = {0.f, 0.f}, a1hi = {0.f, 0.f};
    float2v a2lo = {0.f, 0.f}, a2hi = {0.f, 0.f};
    int s = start;
    while (s < end) {
        int take = end - s;
        if (take > 64) take = 64;
        int li = s + lane;
        int4 rec = edges[(li < end) ? li : (end - 1)];
        for (int j0 = 0; j0 < take; j0 += 8) {
            int src[4];
            float w1[4], w2[4];
#pragma unroll
            for (int pp = 0; pp < 4; pp++) {
                int j = j0 + pp * 2 + half;
                // j >= 64 wraps mod 64 in HW (valid record; weights zeroed below)
                src[pp] = __shfl(rec.x, j, 64);
                float ww1 = bits_to_f((unsigned int)__shfl(rec.y, j, 64));
                float ww2 = bits_to_f((unsigned int)__shfl(rec.z, j, 64));
                int ok = j < take;
                w1[pp] = ok ? ww1 : 0.f;
                w2[pp] = ok ? ww2 : 0.f;
            }
            uint2 q[4];
#pragma unroll
            for (int pp = 0; pp < 4; pp++)
                q[pp] = *(const uint2*)(X + src[pp] * DD + e0);
#pragma unroll
            for (int pp = 0; pp < 4; pp++) {
                float2v xa = { bits_to_f(q[pp].x << 16),
                               bits_to_f(q[pp].x & 0xFFFF0000u) };
                float2v xb = { bits_to_f(q[pp].y << 16),
                               bits_to_f(q[pp].y & 0xFFFF0000u) };
                a1lo += w1[pp] * xa;
                a1hi += w1[pp] * xb;
                a2lo += w2[pp] * xa;
                a2hi += w2[pp] * xb;
            }
        }
        s += take;
    }
    // cross-half exchange: half0 needs partner's a1, half1 needs partner's a2.
    // Each lane SENDS what its partner needs: half0 sends a2, half1 sends a1.
    float2v sendlo = half ? a1lo : a2lo;
    float2v sendhi = half ? a1hi : a2hi;
    float2v keeplo = half ? a2lo : a1lo;
    float2v keephi = half ? a2hi : a1hi;
    float2v tlo, thi;
    tlo.x = keeplo.x + __shfl_xor(sendlo.x, 32, 64);
    tlo.y = keeplo.y + __shfl_xor(sendlo.y, 32, 64);
    thi.x = keephi.x + __shfl_xor(sendhi.x, 32, 64);
    thi.y = keephi.y + __shfl_xor(sendhi.y, 32, 64);
    // analytic self loop, branch-free: a1 += dn^2 * x_self ; a2 += 1 * x_self
    uint2 qs = *(const uint2*)(X + wave * DD + e0);
    float f = half ? 1.0f : dn * dn;
    tlo.x += f * bits_to_f(qs.x << 16);
    tlo.y += f * bits_to_f(qs.x & 0xFFFF0000u);
    thi.x += f * bits_to_f(qs.y << 16);
    thi.y += f * bits_to_f(qs.y & 0xFFFF0000u);
    unsigned int p0 = (unsigned int)f_to_bfbits(tlo.x) |
                      ((unsigned int)f_to_bfbits(tlo.y) << 16);
    unsigned int p1 = (unsigned int)f_to_bfbits(thi.x) |
                      ((unsigned int)f_to_bfbits(thi.y) << 16);
    uint2 outv;
    outv.x = p0;
    outv.y = p1;
    // half0 writes a1 region [0,128), half1 writes a2 region [128,256): one
    // contiguous 512B wave store.
    *(uint2*)(acat + wave * 256 + half * 128 + e0) = outv;
}

// ---------------- Launch ----------------

#define PADUP(x) (((x) + 255) & ~(size_t)255)

extern "C" void kernel_launch(void* const* d_in, const int* in_sizes, int n_in,
                              void* d_out, int out_size, void* d_ws, size_t ws_size,
                              hipStream_t stream) {
    (void)in_sizes; (void)n_in; (void)out_size; (void)ws_size;

    const void* x    = d_in[0];
    const void* d2an = d_in[1];
    const int*  ei0  = (const int*)d_in[2];
    const void* ea0  = d_in[3];
    const int*  ei1  = (const int*)d_in[4];
    const void* ea1  = d_in[5];

    char* p = (char*)d_ws;
    unsigned short* xpe1 = (unsigned short*)p; p += PADUP((size_t)NN * DD * 2);
    unsigned short* xpe2 = (unsigned short*)p; p += PADUP((size_t)NN * DD * 2);
    unsigned short* x0b  = (unsigned short*)p; p += PADUP((size_t)NN * DD * 2);
    unsigned short* xm   = (unsigned short*)p; p += PADUP((size_t)NN * DD * 2);
    unsigned short* xcat = (unsigned short*)p; p += PADUP((size_t)NN * 256 * 2);
    unsigned short* acat0 = xcat;              // xcat dead after PE GEMM
    unsigned short* acat1 = (unsigned short*)p; p += PADUP((size_t)NN * 256 * 2);
    unsigned short* wt   = (unsigned short*)p; p += PADUP((size_t)6 * WSLOT * 2);
    int*   deg0 = (int*)p;    p += PADUP((size_t)NN * 4);
    int*   cur0 = (int*)p;    p += PADUP((size_t)NN * 4);
    float* dis0 = (float*)p;  p += PADUP((size_t)NN * 4);
    int*   deg1 = (int*)p;    p += PADUP((size_t)NN * 4);
    int*   cur1 = (int*)p;    p += PADUP((size_t)NN * 4);
    float* dis1 = (float*)p;  p += PADUP((size_t)NN * 4);
    int4*  edges0 = (int4*)p; p += PADUP((size_t)NE * 16);
    int4*  edges1 = (int4*)p; p += PADUP((size_t)NE * 16);
    int*   bsum = (int*)p;    p += PADUP((size_t)128 * 4);
    int*   boff = (int*)p;    p += PADUP((size_t)128 * 4);
    int*   dflag = (int*)p;

    // rank buffers alias xpe1/xpe2: written by k_hist, consumed by k_fill,
    // both strictly before k_gemm_pe writes xpe1/xpe2 (stream-ordered).
    int* rank0 = (int*)xpe1;   // NE*4 = 6.4MB <= NN*DD*2 = 12.8MB
    int* rank1 = (int*)xpe2;

    // 1. detect + zero degrees
    k_detect0<<<392, 256, 0, stream>>>((const unsigned int*)x, dflag, (float*)d_out,
                                       deg0, deg1);
    // 2. histogram(+rank) — UNFUSED, full-machine occupancy, 8-deep atomic ILP
    k_hist<<<dim3(HIST8B, 2), 256, 0, stream>>>(ei0, ei1, deg0, deg1, rank0, rank1);
    // 3. prepx + weight prep (pure streaming)
    kA<<<PREPXB + PREPB, 256, 0, stream>>>(
        x, d2an, xcat,
        d_in[6], d_in[7], d_in[8], d_in[9], d_in[10], d_in[11], d_in[12],
        d_in[13], d_in[14], d_in[15], wt, dflag);
    // 4-6. parallel scan
    k_scan1<<<dim3(NB, 2), 256, 0, stream>>>(deg0, deg1, dis0, dis1, bsum, NN);
    k_scan2<<<1, 128, 0, stream>>>(bsum, boff);
    k_scan3<<<dim3(NB, 2), 256, 0, stream>>>(deg0, deg1, boff, cur0, cur1, NN);
    // 7. edge fill — atomic-free via ranks
    k_fill<<<dim3(FILLB, 2), 256, 0, stream>>>(ei0, ea0, dis0, cur0, rank0, edges0,
                                               ei1, ea1, dis1, cur1, rank1, edges1,
                                               dflag);
    // 8. PE GEMM: xpe1/xpe2 = xcat @ nodeLin{1,2}   (overwrites rank buffers; ok)
    k_gemm_pe<<<dim3(GX, 2), 256, 0, stream>>>(xcat, wt, xpe1, xpe2);
    // 9. dual agg round 1: acat0 = agg0(xpe1), acat1 = agg1(xpe2)
    k_aggd<<<2 * AGGB, 256, 0, stream>>>(edges0, cur0, deg0, dis0, xpe1, acat0,
                                         edges1, cur1, deg1, dis1, xpe2, acat1);
    // 10. x0 = relu(acat0 @ Wcat_1) -> x0b
    k_gemmL<<<GX, 256, 0, stream>>>(acat0, wt + 2 * WSLOT,
                                    (const unsigned short*)0, x0b, (void*)0,
                                    dflag, 1);
    // 11. xm = 0.5*relu(acat1 @ Wcat_2) + 0.5*x0b
    k_gemmL<<<GX, 256, 0, stream>>>(acat1, wt + 3 * WSLOT, x0b, xm, (void*)0,
                                    dflag, 2);
    // 12. dual agg round 2: acat0 = agg0(xm), acat1 = agg1(xm)
    k_aggd<<<2 * AGGB, 256, 0, stream>>>(edges0, cur0, deg0, dis0, xm, acat0,
                                         edges1, cur1, deg1, dis1, xm, acat1);
    // 13. x0 = relu(acat0 @ Wcat_3) -> x0b
    k_gemmL<<<GX, 256, 0, stream>>>(acat0, wt + 4 * WSLOT,
                                    (const unsigned short*)0, x0b, (void*)0,
                                    dflag, 1);
    // 14. out = 0.5*relu(acat1 @ Wcat_4) + 0.5*x0b  (bf16/f32 per dflag)
    k_gemmL<<<GX, 256, 0, stream>>>(acat1, wt + 5 * WSLOT, x0b,
                                    (unsigned short*)0, d_out, dflag, 3);
}

// Round 9
// 434.121 us; speedup vs baseline: 1.1373x; 1.1090x over previous
//
#include <hip/hip_runtime.h>

#define NN 50000
#define NE 800000
#define DD 128
#define PEW 98
#define KPE 226
#define WSLOT 32768   // bf16 elements per weight slot (128 n x 256 k)
#define NB 49         // scan blocks per level: ceil(NN/1024)
#define GX 782        // ceil(NN/64) gemm row-tiles
#define HIST8B 391    // ceil(NE/(256*8)) hist blocks per level (8 edges/thread)
#define FILLB 782     // ceil(NE/(256*4)) fill blocks per level
#define PREPXB 6250   // NN*256/(256*8) prepx blocks (8 elems/thread)
#define PREPB 48      // 6 slots x 8 tile-blocks
#define AGGB 12500    // ceil(NN/4): 1 wave per node, 4 nodes/block

typedef __attribute__((ext_vector_type(8))) short short8;
typedef __attribute__((ext_vector_type(4))) float float4v;
typedef __attribute__((ext_vector_type(2))) float float2v;

// Kept so anything that looks up the original kernel name still finds a symbol.
__global__ void GraphTrajSTEncoder_67362267070834_kernel() {}

// ---------------- dtype helpers ----------------

__device__ __forceinline__ float bfbits_to_f(unsigned int u16) {
    unsigned int v = u16 << 16;
    float f;
    __builtin_memcpy(&f, &v, 4);
    return f;
}

__device__ __forceinline__ float bits_to_f(unsigned int v) {
    float f;
    __builtin_memcpy(&f, &v, 4);
    return f;
}

__device__ __forceinline__ int f_as_i(float f) {
    int i;
    __builtin_memcpy(&i, &f, 4);
    return i;
}

__device__ __forceinline__ unsigned short f_to_bfbits(float f) {
    unsigned int b;
    __builtin_memcpy(&b, &f, 4);
    unsigned int r = b + 0x7FFFu + ((b >> 16) & 1u);   // round to nearest even
    return (unsigned short)(r >> 16);
}

__device__ __forceinline__ float ldf(const void* p, int i, int isbf) {
    if (isbf) return bfbits_to_f(((const unsigned short*)p)[i]);
    return ((const float*)p)[i];
}

// ---------------- dispatch 1: dtype detect + zero degree arrays ----------------
__global__ __launch_bounds__(256)
void k_detect0(const unsigned int* xw, int* flag, float* dout_sentinel,
               int* deg0, int* deg1) {
    if (blockIdx.x == 0) {
        __shared__ int cnt;
        if (threadIdx.x == 0) cnt = 0;
        __syncthreads();
        unsigned int w = xw[threadIdx.x];
        unsigned int e = (w >> 7) & 0xFFu;
        atomicAdd(&cnt, (e >= 100u && e <= 150u) ? 1 : 0);
        __syncthreads();
        if (threadIdx.x == 0) {
            flag[0] = (cnt >= 128) ? 1 : 0;
            dout_sentinel[0] = 1.0e6f;
        }
    } else {
        int i = (blockIdx.x - 1) * 256 + threadIdx.x;
        if (i < NN) deg0[i] = 0;
        else if (i < 2 * NN) deg1[i - NN] = 0;
    }
}

// ---------- dispatch 2 (kB): FUSED hist(+rank, 8-edge ILP) + prepx + wprep ----
// The atomic histogram is a ~21 G-atomic/s memory-side floor (~75 us); the
// streaming prepx/wprep waves run under its latency shadow. Hist blocks first.
__global__ __launch_bounds__(256)
void kB(const int* __restrict__ ei0, const int* __restrict__ ei1,
        int* deg0, int* deg1,
        int* __restrict__ rank0, int* __restrict__ rank1,
        const void* x, const void* pe, unsigned short* __restrict__ xcat,
        const void* n1, const void* n2,
        const void* l11, const void* l21, const void* l12, const void* l22,
        const void* l13, const void* l23, const void* l14, const void* l24,
        unsigned short* __restrict__ wt, const int* __restrict__ dflag) {
    int b = blockIdx.x;
    int t = threadIdx.x;
    if (b < 2 * HIST8B) {
        int lvl = b >= HIST8B;
        const int* col = (lvl ? ei1 : ei0) + NE;
        int* deg = lvl ? deg1 : deg0;
        int* rank = lvl ? rank1 : rank0;
        int i0 = ((b - (lvl ? HIST8B : 0)) * 256 + t) * 8;
        if (i0 >= NE) return;   // NE % 8 == 0 -> full octets only
        int4 ca = *(const int4*)(col + i0);
        int4 cb = *(const int4*)(col + i0 + 4);
        int4 ra, rb;
        ra.x = atomicAdd(&deg[ca.x], 1);
        ra.y = atomicAdd(&deg[ca.y], 1);
        ra.z = atomicAdd(&deg[ca.z], 1);
        ra.w = atomicAdd(&deg[ca.w], 1);
        rb.x = atomicAdd(&deg[cb.x], 1);
        rb.y = atomicAdd(&deg[cb.y], 1);
        rb.z = atomicAdd(&deg[cb.z], 1);
        rb.w = atomicAdd(&deg[cb.w], 1);
        *(int4*)(rank + i0) = ra;
        *(int4*)(rank + i0 + 4) = rb;
    } else if (b < 2 * HIST8B + PREPXB) {
        int isbf = dflag[0];
        int id0 = (b - 2 * HIST8B) * 2048 + t * 8;
        int row = id0 >> 8, c0 = id0 & 255;   // c0 is a multiple of 8
        union { unsigned short u[8]; short8 v; } ob;
        if (c0 < DD) {
            // 8 consecutive x columns
            if (isbf) {
                ob.v = *(const short8*)((const unsigned short*)x + row * DD + c0);
            } else {
                float f[8];
                __builtin_memcpy(f, (const float*)x + row * DD + c0, 32);
#pragma unroll
                for (int j = 0; j < 8; j++) ob.u[j] = f_to_bfbits(f[j]);
            }
        } else if (c0 + 8 <= KPE) {
            // 8 consecutive pe columns (c0 = 128..216)
            int off = row * PEW + (c0 - DD);
            if (isbf) {
                unsigned short tmp[8];
                __builtin_memcpy(tmp, (const unsigned short*)pe + off, 16);
#pragma unroll
                for (int j = 0; j < 8; j++) ob.u[j] = tmp[j];
            } else {
                float f[8];
                __builtin_memcpy(f, (const float*)pe + off, 32);
#pragma unroll
                for (int j = 0; j < 8; j++) ob.u[j] = f_to_bfbits(f[j]);
            }
        } else {
            // mixed tail (c0 = 224) or pure zero pad (c0 = 232/240/248)
#pragma unroll
            for (int j = 0; j < 8; j++) {
                int c = c0 + j;
                float v = 0.f;
                if (c < KPE) v = ldf(pe, row * PEW + (c - DD), isbf);
                ob.u[j] = f_to_bfbits(v);
            }
        }
        *(short8*)(xcat + id0) = ob.v;
    } else {
        int b3 = b - 2 * HIST8B - PREPXB;
        int y = b3 >> 3, bx = b3 & 7;
        int kt = bx >> 1, nt = bx & 1;
        __shared__ float tile[64][65];
        int cc = t & 63, rr = t >> 6;
        int k0 = kt * 64, n0 = nt * 64;
        int isbf = dflag[0];
        const void* sA;   // source for k<128
        const void* sB;   // source for k>=128
        if (y == 0)      { sA = n1;  sB = n1; }
        else if (y == 1) { sA = n2;  sB = n2; }
        else if (y == 2) { sA = l11; sB = l21; }
        else if (y == 3) { sA = l12; sB = l22; }
        else if (y == 4) { sA = l13; sB = l23; }
        else             { sA = l14; sB = l24; }
#pragma unroll
        for (int i = 0; i < 16; i++) {
            int k = k0 + rr + i * 4;
            float v = 0.f;
            if (y < 2) {
                if (k < KPE) v = ldf(sA, k * DD + n0 + cc, isbf);
            } else {
                v = (k < 128) ? ldf(sA, k * DD + n0 + cc, isbf)
                              : ldf(sB, (k - 128) * DD + n0 + cc, isbf);
            }
            tile[rr + i * 4][cc] = v;
        }
        __syncthreads();
        unsigned short* w = wt + y * WSLOT;
#pragma unroll
        for (int i = 0; i < 16; i++) {
            int nn = rr + i * 4;
            w[(n0 + nn) * 256 + k0 + cc] = f_to_bfbits(tile[cc][nn]);
        }
    }
}

// ---------------- parallel scan (deg = real edges; dis = rsqrt(deg+1)) -----------
__global__ void k_scan1(const int* __restrict__ deg0, const int* __restrict__ deg1,
                        float* __restrict__ dis0, float* __restrict__ dis1,
                        int* __restrict__ bsum, int n) {
    int l = blockIdx.y;
    const int* deg = l ? deg1 : deg0;
    float* dis = l ? dis1 : dis0;
    int t = threadIdx.x;
    int base = blockIdx.x * 1024 + t * 4;
    int d[4] = {0, 0, 0, 0};
    if (base + 3 < n) {
        int4 q = *(const int4*)(deg + base);
        d[0] = q.x; d[1] = q.y; d[2] = q.z; d[3] = q.w;
    } else {
#pragma unroll
        for (int j = 0; j < 4; j++) if (base + j < n) d[j] = deg[base + j];
    }
#pragma unroll
    for (int j = 0; j < 4; j++)
        if (base + j < n) dis[base + j] = rsqrtf((float)(d[j] + 1));
    int s = d[0] + d[1] + d[2] + d[3];
#pragma unroll
    for (int off = 32; off >= 1; off >>= 1) s += __shfl_down(s, off, 64);
    __shared__ int ws[4];
    if ((t & 63) == 0) ws[t >> 6] = s;
    __syncthreads();
    if (t == 0) bsum[l * 64 + blockIdx.x] = ws[0] + ws[1] + ws[2] + ws[3];
}

__global__ void k_scan2(const int* __restrict__ bsum, int* __restrict__ boff) {
    int lane = threadIdx.x & 63;
    int l = threadIdx.x >> 6;
    int v = (lane < NB) ? bsum[l * 64 + lane] : 0;
    int s = v;
#pragma unroll
    for (int off = 1; off < 64; off <<= 1) {
        int u = __shfl_up(s, off, 64);
        if (lane >= off) s += u;
    }
    boff[l * 64 + lane] = s - v;   // exclusive
}

__global__ void k_scan3(const int* __restrict__ deg0, const int* __restrict__ deg1,
                        const int* __restrict__ boff,
                        int* __restrict__ cur0, int* __restrict__ cur1, int n) {
    int l = blockIdx.y;
    const int* deg = l ? deg1 : deg0;
    int* cur = l ? cur1 : cur0;
    int t = threadIdx.x;
    int base = blockIdx.x * 1024 + t * 4;
    int d[4] = {0, 0, 0, 0};
    if (base + 3 < n) {
        int4 q = *(const int4*)(deg + base);
        d[0] = q.x; d[1] = q.y; d[2] = q.z; d[3] = q.w;
    } else {
#pragma unroll
        for (int j = 0; j < 4; j++) if (base + j < n) d[j] = deg[base + j];
    }
    int s = d[0] + d[1] + d[2] + d[3];
    __shared__ int sc[256];
    sc[t] = s;
    __syncthreads();
    for (int off = 1; off < 256; off <<= 1) {
        int v = (t >= off) ? sc[t - off] : 0;
        __syncthreads();
        sc[t] += v;
        __syncthreads();
    }
    int p = boff[l * 64 + blockIdx.x] + sc[t] - s;   // exclusive prefix
#pragma unroll
    for (int j = 0; j < 4; j++) {
        if (base + j < n) { cur[base + j] = p; p += d[j]; }
    }
}

// ---------------- GEMM core: 64x128 tile, K=256, bf16 MFMA ----------------
__device__ __forceinline__ void gemm_core(const unsigned short* __restrict__ A,
                                          const unsigned short* __restrict__ wt,
                                          int row0, float4v acc[8]) {
    __shared__ short A_s[64 * 72];
    __shared__ short B_s[128 * 72];
    int tid = threadIdx.x;
    int lane = tid & 63, w = tid >> 6;
    int m = lane & 15, quad = lane >> 4;
#pragma unroll
    for (int t = 0; t < 8; t++) acc[t] = (float4v){0.f, 0.f, 0.f, 0.f};
    for (int c = 0; c < 4; c++) {
#pragma unroll
        for (int i = 0; i < 2; i++) {
            int e = (i * 256 + tid) * 8;
            int r = e >> 6, cc = e & 63;
            int rr = row0 + r;
            short8 v = {0, 0, 0, 0, 0, 0, 0, 0};
            if (rr < NN) v = *(const short8*)(A + rr * 256 + c * 64 + cc);
            *(short8*)&A_s[r * 72 + cc] = v;
        }
#pragma unroll
        for (int i = 0; i < 4; i++) {
            int e = (i * 256 + tid) * 8;
            int nr = e >> 6, kk = e & 63;
            *(short8*)&B_s[nr * 72 + kk] = *(const short8*)(wt + nr * 256 + c * 64 + kk);
        }
        __syncthreads();
#pragma unroll
        for (int c2 = 0; c2 < 2; c2++) {
            short8 a = *(short8*)&A_s[(w * 16 + m) * 72 + c2 * 32 + quad * 8];
#pragma unroll
            for (int t = 0; t < 8; t++) {
                short8 b = *(short8*)&B_s[(t * 16 + m) * 72 + c2 * 32 + quad * 8];
                acc[t] = __builtin_amdgcn_mfma_f32_16x16x32_bf16(a, b, acc[t], 0, 0, 0);
            }
        }
        __syncthreads();
    }
}

// ---- dispatch 7 (k_fillpe): FUSED edge-fill + PE GEMM (independent work) ----
// fill: position = cur_start[col] + rank[i], atomic-free, 4 edges/thread.
// gemm_pe: xpe{1,2} = xcat @ nodeLin{1,2}.
__global__ __launch_bounds__(256)
void k_fillpe(const int* __restrict__ ei0, const void* __restrict__ ea0,
              const float* __restrict__ dis0, const int* __restrict__ cur0,
              const int* __restrict__ rank0, int4* __restrict__ edges0,
              const int* __restrict__ ei1, const void* __restrict__ ea1,
              const float* __restrict__ dis1, const int* __restrict__ cur1,
              const int* __restrict__ rank1, int4* __restrict__ edges1,
              const unsigned short* __restrict__ xcat,
              const unsigned short* __restrict__ wt,
              unsigned short* __restrict__ xpe1, unsigned short* __restrict__ xpe2,
              const int* __restrict__ dflag) {
    int b = blockIdx.x;
    if (b < 2 * FILLB) {
        int lvl = b >= FILLB;
        const int* row = lvl ? ei1 : ei0;
        const int* col = row + NE;
        const void* attr = lvl ? ea1 : ea0;
        const float* dis = lvl ? dis1 : dis0;
        const int* cur = lvl ? cur1 : cur0;
        const int* rank = lvl ? rank1 : rank0;
        int4* edges = lvl ? edges1 : edges0;
        int i0 = ((b - (lvl ? FILLB : 0)) * 256 + threadIdx.x) * 4;
        if (i0 >= NE) return;   // NE % 4 == 0 -> full quads only
        int4 rr = *(const int4*)(row + i0);
        int4 cc = *(const int4*)(col + i0);
        int4 rk = *(const int4*)(rank + i0);
        int isbf = dflag[0];
        float a[4];
        if (isbf) {
            unsigned short tmp[4];
            __builtin_memcpy(tmp, (const unsigned short*)attr + i0, 8);
#pragma unroll
            for (int j = 0; j < 4; j++) a[j] = bfbits_to_f(tmp[j]);
        } else {
            __builtin_memcpy(a, (const float*)attr + i0, 16);
        }
        int rv[4] = {rr.x, rr.y, rr.z, rr.w};
        int cv[4] = {cc.x, cc.y, cc.z, cc.w};
        int kv[4] = {rk.x, rk.y, rk.z, rk.w};
#pragma unroll
        for (int j = 0; j < 4; j++) {
            int p = cur[cv[j]] + kv[j];
            float w2 = (a[j] > 0.f) ? fminf(rsqrtf(a[j]), 1.f) : 0.f;
            int4 rec;
            rec.x = rv[j];
            rec.y = f_as_i(dis[rv[j]] * dis[cv[j]]);
            rec.z = f_as_i(w2);
            rec.w = 0;
            edges[p] = rec;
        }
    } else {
        int g = b - 2 * FILLB;
        int y = g >= GX;
        int bx = g - (y ? GX : 0);
        float4v acc[8];
        gemm_core(xcat, wt + (y ? WSLOT : 0), bx * 64, acc);
        unsigned short* out = y ? xpe2 : xpe1;
        int lane = threadIdx.x & 63, w = threadIdx.x >> 6;
        int m = lane & 15, quad = lane >> 4;
        int row0 = bx * 64;
#pragma unroll
        for (int t = 0; t < 8; t++)
#pragma unroll
            for (int r = 0; r < 4; r++) {
                int row = row0 + w * 16 + quad * 4 + r;
                if (row < NN) out[row * DD + t * 16 + m] = f_to_bfbits(acc[t][r]);
            }
    }
}

// ---- double-layer GEMM: out = 0.5*relu(acatA@wtA) + 0.5*relu(acatB@wtB) ----
// Fuses the former mode-1 + mode-2 pair; x0b intermediate eliminated.
// final_mode 0: bf16 -> outBf. final_mode 1: bf16/f32 per dflag -> outFinal.
__global__ __launch_bounds__(256)
void k_gemmL2(const unsigned short* __restrict__ acatA,
              const unsigned short* __restrict__ wtA,
              const unsigned short* __restrict__ acatB,
              const unsigned short* __restrict__ wtB,
              unsigned short* __restrict__ outBf, void* __restrict__ outFinal,
              const int* __restrict__ dflag, int final_mode) {
    float4v accA[8], accB[8];
    gemm_core(acatA, wtA, blockIdx.x * 64, accA);
    gemm_core(acatB, wtB, blockIdx.x * 64, accB);
    int lane = threadIdx.x & 63, w = threadIdx.x >> 6;
    int m = lane & 15, quad = lane >> 4;
    int row0 = blockIdx.x * 64;
    int isbf = final_mode ? dflag[0] : 1;
#pragma unroll
    for (int t = 0; t < 8; t++) {
        int colc = t * 16 + m;
#pragma unroll
        for (int r = 0; r < 4; r++) {
            int row = row0 + w * 16 + quad * 4 + r;
            if (row >= NN) continue;
            float v = 0.5f * fmaxf(accA[t][r], 0.f) + 0.5f * fmaxf(accB[t][r], 0.f);
            if (final_mode && !isbf)
                ((float*)outFinal)[row * DD + colc] = v;
            else if (final_mode)
                ((unsigned short*)outFinal)[row * DD + colc] = f_to_bfbits(v);
            else
                outBf[row * DD + colc] = f_to_bfbits(v);
        }
    }
}

// ---------------- dual-level aggregation over X (a1|a2 -> acat[N,256]) ----------
// 1 wave per node, PAIR-PROCESSED: lanes 0-31 handle edge j, lanes 32-63 edge
// j+1; each lane owns 4 columns (8B uint2 gather). Lane-tiled record read +
// __shfl broadcast with per-lane index (j+half). Packed float2 FMAs. Epilogue:
// single cross-half exchange (half0 keeps a1, half1 keeps a2), branch-free
// self-loop via per-half scale, one coalesced 8B store per lane.
// cur[] holds START offsets.
__global__ __launch_bounds__(256)
void k_aggd(const int4* __restrict__ edges0, const int* __restrict__ cur0,
            const int* __restrict__ deg0, const float* __restrict__ dis0,
            const unsigned short* __restrict__ X0, unsigned short* __restrict__ acat0,
            const int4* __restrict__ edges1, const int* __restrict__ cur1,
            const int* __restrict__ deg1, const float* __restrict__ dis1,
            const unsigned short* __restrict__ X1, unsigned short* __restrict__ acat1) {
    int b = blockIdx.x;
    int lvl = b >= AGGB;
    const int4* edges = lvl ? edges1 : edges0;
    const int* cur = lvl ? cur1 : cur0;
    const int* deg = lvl ? deg1 : deg0;
    const float* dis = lvl ? dis1 : dis0;
    const unsigned short* X = lvl ? X1 : X0;
    unsigned short* acat = lvl ? acat1 : acat0;
    int wave = ((b - (lvl ? AGGB : 0)) * 256 + threadIdx.x) >> 6;
    int lane = threadIdx.x & 63;
    if (wave >= NN) return;
    int half = lane >> 5;          // which edge of each pair this lane serves
    int sub = lane & 31;           // 32 lanes per edge-row
    int e0 = sub * 4;              // first of this lane's 4 bf16 columns
    int start = cur[wave];
    int d = deg[wave];
    int end = start + d;
    float dn = dis[wave];
    float2v a1lo = {0.f, 0.f}, a1hi = {0.f, 0.f};
    float2v a2lo = {0.f, 0.f}, a2hi = {0.f, 0.f};
    int s = start;
    while (s < end) {
        int take = end - s;
        if (take > 64) take = 64;
        int li = s + lane;
        int4 rec = edges[(li < end) ? li : (end - 1)];
        for (int j0 = 0; j0 < take; j0 += 8) {
            int src[4];
            float w1[4], w2[4];
#pragma unroll
            for (int pp = 0; pp < 4; pp++) {
                int j = j0 + pp * 2 + half;
                // j >= 64 wraps mod 64 in HW (valid record; weights zeroed below)
                src[pp] = __shfl(rec.x, j, 64);
                float ww1 = bits_to_f((unsigned int)__shfl(rec.y, j, 64));
                float ww2 = bits_to_f((unsigned int)__shfl(rec.z, j, 64));
                int ok = j < take;
                w1[pp] = ok ? ww1 : 0.f;
                w2[pp] = ok ? ww2 : 0.f;
            }
            uint2 q[4];
#pragma unroll
            for (int pp = 0; pp < 4; pp++)
                q[pp] = *(const uint2*)(X + src[pp] * DD + e0);
#pragma unroll
            for (int pp = 0; pp < 4; pp++) {
                float2v xa = { bits_to_f(q[pp].x << 16),
                               bits_to_f(q[pp].x & 0xFFFF0000u) };
                float2v xb = { bits_to_f(q[pp].y << 16),
                               bits_to_f(q[pp].y & 0xFFFF0000u) };
                a1lo += w1[pp] * xa;
                a1hi += w1[pp] * xb;
                a2lo += w2[pp] * xa;
                a2hi += w2[pp] * xb;
            }
        }
        s += take;
    }
    // cross-half exchange: half0 needs partner's a1, half1 needs partner's a2.
    // Each lane SENDS what its partner needs: half0 sends a2, half1 sends a1.
    float2v sendlo = half ? a1lo : a2lo;
    float2v sendhi = half ? a1hi : a2hi;
    float2v keeplo = half ? a2lo : a1lo;
    float2v keephi = half ? a2hi : a1hi;
    float2v tlo, thi;
    tlo.x = keeplo.x + __shfl_xor(sendlo.x, 32, 64);
    tlo.y = keeplo.y + __shfl_xor(sendlo.y, 32, 64);
    thi.x = keephi.x + __shfl_xor(sendhi.x, 32, 64);
    thi.y = keephi.y + __shfl_xor(sendhi.y, 32, 64);
    // analytic self loop, branch-free: a1 += dn^2 * x_self ; a2 += 1 * x_self
    uint2 qs = *(const uint2*)(X + wave * DD + e0);
    float f = half ? 1.0f : dn * dn;
    tlo.x += f * bits_to_f(qs.x << 16);
    tlo.y += f * bits_to_f(qs.x & 0xFFFF0000u);
    thi.x += f * bits_to_f(qs.y << 16);
    thi.y += f * bits_to_f(qs.y & 0xFFFF0000u);
    unsigned int p0 = (unsigned int)f_to_bfbits(tlo.x) |
                      ((unsigned int)f_to_bfbits(tlo.y) << 16);
    unsigned int p1 = (unsigned int)f_to_bfbits(thi.x) |
                      ((unsigned int)f_to_bfbits(thi.y) << 16);
    uint2 outv;
    outv.x = p0;
    outv.y = p1;
    // half0 writes a1 region [0,128), half1 writes a2 region [128,256): one
    // contiguous 512B wave store.
    *(uint2*)(acat + wave * 256 + half * 128 + e0) = outv;
}

// ---------------- Launch ----------------

#define PADUP(x) (((x) + 255) & ~(size_t)255)

extern "C" void kernel_launch(void* const* d_in, const int* in_sizes, int n_in,
                              void* d_out, int out_size, void* d_ws, size_t ws_size,
                              hipStream_t stream) {
    (void)in_sizes; (void)n_in; (void)out_size; (void)ws_size;

    const void* x    = d_in[0];
    const void* d2an = d_in[1];
    const int*  ei0  = (const int*)d_in[2];
    const void* ea0  = d_in[3];
    const int*  ei1  = (const int*)d_in[4];
    const void* ea1  = d_in[5];

    char* p = (char*)d_ws;
    unsigned short* xpe1 = (unsigned short*)p; p += PADUP((size_t)NN * DD * 2);
    unsigned short* xpe2 = (unsigned short*)p; p += PADUP((size_t)NN * DD * 2);
    unsigned short* xm   = (unsigned short*)p; p += PADUP((size_t)NN * DD * 2);
    unsigned short* xcat = (unsigned short*)p; p += PADUP((size_t)NN * 256 * 2);
    unsigned short* acat0 = xcat;              // xcat dead after PE GEMM
    unsigned short* acat1 = (unsigned short*)p; p += PADUP((size_t)NN * 256 * 2);
    unsigned short* wt   = (unsigned short*)p; p += PADUP((size_t)6 * WSLOT * 2);
    int*   deg0 = (int*)p;    p += PADUP((size_t)NN * 4);
    int*   cur0 = (int*)p;    p += PADUP((size_t)NN * 4);
    float* dis0 = (float*)p;  p += PADUP((size_t)NN * 4);
    int*   deg1 = (int*)p;    p += PADUP((size_t)NN * 4);
    int*   cur1 = (int*)p;    p += PADUP((size_t)NN * 4);
    float* dis1 = (float*)p;  p += PADUP((size_t)NN * 4);
    int4*  edges0 = (int4*)p; p += PADUP((size_t)NE * 16);
    int4*  edges1 = (int4*)p; p += PADUP((size_t)NE * 16);
    int*   bsum = (int*)p;    p += PADUP((size_t)128 * 4);
    int*   boff = (int*)p;    p += PADUP((size_t)128 * 4);
    int*   rank0 = (int*)p;   p += PADUP((size_t)NE * 4);   // dedicated (no alias):
    int*   rank1 = (int*)p;   p += PADUP((size_t)NE * 4);   // fill runs concurrent w/ PE GEMM
    int*   dflag = (int*)p;

    // 1. detect + zero degrees
    k_detect0<<<392, 256, 0, stream>>>((const unsigned int*)x, dflag, (float*)d_out,
                                       deg0, deg1);
    // 2. FUSED: hist(+rank, 8-edge ILP) + prepx + weight prep.
    //    Streaming waves hide under the ~75us memory-side atomic floor.
    kB<<<2 * HIST8B + PREPXB + PREPB, 256, 0, stream>>>(
        ei0, ei1, deg0, deg1, rank0, rank1, x, d2an, xcat,
        d_in[6], d_in[7], d_in[8], d_in[9], d_in[10], d_in[11], d_in[12],
        d_in[13], d_in[14], d_in[15], wt, dflag);
    // 3-5. parallel scan
    k_scan1<<<dim3(NB, 2), 256, 0, stream>>>(deg0, deg1, dis0, dis1, bsum, NN);
    k_scan2<<<1, 128, 0, stream>>>(bsum, boff);
    k_scan3<<<dim3(NB, 2), 256, 0, stream>>>(deg0, deg1, boff, cur0, cur1, NN);
    // 6. FUSED: edge fill (atomic-free) + PE GEMM (independent work items)
    k_fillpe<<<2 * FILLB + 2 * GX, 256, 0, stream>>>(
        ei0, ea0, dis0, cur0, rank0, edges0,
        ei1, ea1, dis1, cur1, rank1, edges1,
        xcat, wt, xpe1, xpe2, dflag);
    // 7. dual agg round 1: acat0 = agg0(xpe1), acat1 = agg1(xpe2)
    k_aggd<<<2 * AGGB, 256, 0, stream>>>(edges0, cur0, deg0, dis0, xpe1, acat0,
                                         edges1, cur1, deg1, dis1, xpe2, acat1);
    // 8. xm = 0.5*relu(acat0@W1) + 0.5*relu(acat1@W2)   (x0b eliminated)
    k_gemmL2<<<GX, 256, 0, stream>>>(acat0, wt + 2 * WSLOT,
                                     acat1, wt + 3 * WSLOT,
                                     xm, (void*)0, dflag, 0);
    // 9. dual agg round 2: acat0 = agg0(xm), acat1 = agg1(xm)
    k_aggd<<<2 * AGGB, 256, 0, stream>>>(edges0, cur0, deg0, dis0, xm, acat0,
                                         edges1, cur1, deg1, dis1, xm, acat1);
    // 10. out = 0.5*relu(acat0@W3) + 0.5*relu(acat1@W4)  (bf16/f32 per dflag)
    k_gemmL2<<<GX, 256, 0, stream>>>(acat0, wt + 4 * WSLOT,
                                     acat1, wt + 5 * WSLOT,
                                     (unsigned short*)0, d_out, dflag, 1);
}

// Round 10
// 422.228 us; speedup vs baseline: 1.1694x; 1.0282x over previous
//
#include <hip/hip_runtime.h>

#define NN 50000
#define NE 800000
#define DD 128
#define PEW 98
#define KPE 226
#define WSLOT 32768   // bf16 elements per weight slot (128 n x 256 k)
#define NB 49         // scan blocks per level: ceil(NN/1024)
#define GX 782        // ceil(NN/64) gemm row-tiles
#define NCH 128       // edge chunks per level (LDS hist blocks)
#define CHSZ 6250     // NE / NCH
#define NHALF 25000   // node-range half for LDS hist passes
#define FILLB 782     // ceil(NE/(256*4)) fill blocks per level
#define PREPXB 6250   // NN*256/(256*8) prepx blocks (8 elems/thread)
#define PREPB 48      // 6 slots x 8 tile-blocks
#define SCANBB 391    // ceil(NN/128) node-tiles for k_scanB
#define AGGB 12500    // ceil(NN/4): 1 wave per node, 4 nodes/block

typedef __attribute__((ext_vector_type(8))) short short8;
typedef __attribute__((ext_vector_type(4))) float float4v;
typedef __attribute__((ext_vector_type(2))) float float2v;

// Kept so anything that looks up the original kernel name still finds a symbol.
__global__ void GraphTrajSTEncoder_67362267070834_kernel() {}

// ---------------- dtype helpers ----------------

__device__ __forceinline__ float bfbits_to_f(unsigned int u16) {
    unsigned int v = u16 << 16;
    float f;
    __builtin_memcpy(&f, &v, 4);
    return f;
}

__device__ __forceinline__ float bits_to_f(unsigned int v) {
    float f;
    __builtin_memcpy(&f, &v, 4);
    return f;
}

__device__ __forceinline__ int f_as_i(float f) {
    int i;
    __builtin_memcpy(&i, &f, 4);
    return i;
}

__device__ __forceinline__ unsigned short f_to_bfbits(float f) {
    unsigned int b;
    __builtin_memcpy(&b, &f, 4);
    unsigned int r = b + 0x7FFFu + ((b >> 16) & 1u);   // round to nearest even
    return (unsigned short)(r >> 16);
}

__device__ __forceinline__ float ldf(const void* p, int i, int isbf) {
    if (isbf) return bfbits_to_f(((const unsigned short*)p)[i]);
    return ((const float*)p)[i];
}

// ---------------- dispatch 1: dtype detect ----------------
__global__ __launch_bounds__(256)
void k_detect0(const unsigned int* xw, int* flag, float* dout_sentinel) {
    __shared__ int cnt;
    if (threadIdx.x == 0) cnt = 0;
    __syncthreads();
    unsigned int w = xw[threadIdx.x];
    unsigned int e = (w >> 7) & 0xFFu;
    atomicAdd(&cnt, (e >= 100u && e <= 150u) ? 1 : 0);
    __syncthreads();
    if (threadIdx.x == 0) {
        flag[0] = (cnt >= 128) ? 1 : 0;
        dout_sentinel[0] = 1.0e6f;
    }
}

// ---- dispatch 2 (kB): LDS-hist(+rank) + prepx + wprep — NO GLOBAL ATOMICS ----
// Hist: block owns a 6250-edge chunk; counts into LDS u16 (packed-u32 LDS
// atomics, 2 node-range passes of 25K @ 50KB). LDS atomic return = local rank.
// Per-(chunk,node) counts -> cnt matrix (u16, [lvl][chunk][node]).
// Streaming prepx/wprep blocks share the kernel (smem overlaid).
__global__ __launch_bounds__(256)
void kB(const int* __restrict__ ei0, const int* __restrict__ ei1,
        int* __restrict__ rank0, int* __restrict__ rank1,
        unsigned short* __restrict__ cnt,
        const void* x, const void* pe, unsigned short* __restrict__ xcat,
        const void* n1, const void* n2,
        const void* l11, const void* l21, const void* l12, const void* l22,
        const void* l13, const void* l23, const void* l14, const void* l24,
        unsigned short* __restrict__ wt, const int* __restrict__ dflag) {
    __shared__ unsigned int smem[12800];   // 51.2KB: hist counters / wprep tile
    int b = blockIdx.x;
    int t = threadIdx.x;
    if (b < 2 * NCH) {
        int lvl = b >= NCH;
        int blk = b - (lvl ? NCH : 0);
        const int* col = (lvl ? ei1 : ei0) + NE;
        int* rank = lvl ? rank1 : rank0;
        unsigned short* cnt_row = cnt + (size_t)lvl * NCH * NN + (size_t)blk * NN;
        int cs = blk * CHSZ;
        // cache this thread's cols in registers (static indexing only)
        int myc[25];
#pragma unroll
        for (int k = 0; k < 25; k++) {
            int i = cs + t + k * 256;
            myc[k] = (i < cs + CHSZ) ? col[i] : -1;
        }
#pragma unroll
        for (int pass = 0; pass < 2; pass++) {
            int lo = pass * NHALF;
            for (int w = t; w < NHALF / 2; w += 256) smem[w] = 0;
            __syncthreads();
#pragma unroll
            for (int k = 0; k < 25; k++) {
                int rel = myc[k] - lo;
                if (myc[k] >= 0 && rel >= 0 && rel < NHALF) {
                    unsigned int sh = (unsigned int)(rel & 1) * 16u;
                    unsigned int old = atomicAdd(&smem[rel >> 1], 1u << sh);
                    rank[cs + t + k * 256] = (int)((old >> sh) & 0xFFFFu);
                }
            }
            __syncthreads();
            unsigned int* dst = (unsigned int*)(cnt_row + lo);
            for (int w = t; w < NHALF / 2; w += 256) dst[w] = smem[w];
            __syncthreads();
        }
    } else if (b < 2 * NCH + PREPXB) {
        int isbf = dflag[0];
        int id0 = (b - 2 * NCH) * 2048 + t * 8;
        int row = id0 >> 8, c0 = id0 & 255;   // c0 is a multiple of 8
        union { unsigned short u[8]; short8 v; } ob;
        if (c0 < DD) {
            if (isbf) {
                ob.v = *(const short8*)((const unsigned short*)x + row * DD + c0);
            } else {
                float f[8];
                __builtin_memcpy(f, (const float*)x + row * DD + c0, 32);
#pragma unroll
                for (int j = 0; j < 8; j++) ob.u[j] = f_to_bfbits(f[j]);
            }
        } else if (c0 + 8 <= KPE) {
            int off = row * PEW + (c0 - DD);
            if (isbf) {
                unsigned short tmp[8];
                __builtin_memcpy(tmp, (const unsigned short*)pe + off, 16);
#pragma unroll
                for (int j = 0; j < 8; j++) ob.u[j] = tmp[j];
            } else {
                float f[8];
                __builtin_memcpy(f, (const float*)pe + off, 32);
#pragma unroll
                for (int j = 0; j < 8; j++) ob.u[j] = f_to_bfbits(f[j]);
            }
        } else {
#pragma unroll
            for (int j = 0; j < 8; j++) {
                int c = c0 + j;
                float v = 0.f;
                if (c < KPE) v = ldf(pe, row * PEW + (c - DD), isbf);
                ob.u[j] = f_to_bfbits(v);
            }
        }
        *(short8*)(xcat + id0) = ob.v;
    } else {
        int b3 = b - 2 * NCH - PREPXB;
        int y = b3 >> 3, bx = b3 & 7;
        int kt = bx >> 1, nt = bx & 1;
        float (*tile)[65] = (float(*)[65])smem;   // 16.6KB overlay
        int cc = t & 63, rr = t >> 6;
        int k0 = kt * 64, n0 = nt * 64;
        int isbf = dflag[0];
        const void* sA;   // source for k<128
        const void* sB;   // source for k>=128
        if (y == 0)      { sA = n1;  sB = n1; }
        else if (y == 1) { sA = n2;  sB = n2; }
        else if (y == 2) { sA = l11; sB = l21; }
        else if (y == 3) { sA = l12; sB = l22; }
        else if (y == 4) { sA = l13; sB = l23; }
        else             { sA = l14; sB = l24; }
#pragma unroll
        for (int i = 0; i < 16; i++) {
            int k = k0 + rr + i * 4;
            float v = 0.f;
            if (y < 2) {
                if (k < KPE) v = ldf(sA, k * DD + n0 + cc, isbf);
            } else {
                v = (k < 128) ? ldf(sA, k * DD + n0 + cc, isbf)
                              : ldf(sB, (k - 128) * DD + n0 + cc, isbf);
            }
            tile[rr + i * 4][cc] = v;
        }
        __syncthreads();
        unsigned short* w = wt + y * WSLOT;
#pragma unroll
        for (int i = 0; i < 16; i++) {
            int nn = rr + i * 4;
            w[(n0 + nn) * 256 + k0 + cc] = f_to_bfbits(tile[cc][nn]);
        }
    }
}

// ---- k_scanB: cnt[lvl][blk][node] -> exclusive prefix along blk (in place) ----
// Also emits deg[node] = total. LDS-transposed for coalesced global access.
__global__ __launch_bounds__(256)
void k_scanB(unsigned short* __restrict__ cnt,
             int* __restrict__ deg0, int* __restrict__ deg1) {
    __shared__ unsigned short t16[128 * 132];
    int lvl = blockIdx.y;
    int n0 = blockIdx.x * 128;
    unsigned short* base = cnt + (size_t)lvl * NCH * NN;
    int t = threadIdx.x;
    int brow = t >> 6, colw = t & 63;      // 64 u32 (=128 nodes) per chunk-row
    int node2 = n0 + colw * 2;
    for (int b = brow; b < NCH; b += 4) {
        unsigned int v = 0;
        if (node2 < NN) v = *(const unsigned int*)(base + (size_t)b * NN + node2);
        *(unsigned int*)(&t16[b * 132 + colw * 2]) = v;
    }
    __syncthreads();
    if (t < 128) {
        unsigned int sum = 0;
#pragma unroll
        for (int b = 0; b < NCH; b++) {
            unsigned int v = t16[b * 132 + t];
            t16[b * 132 + t] = (unsigned short)sum;
            sum += v;
        }
        int node = n0 + t;
        if (node < NN) {
            int* deg = lvl ? deg1 : deg0;
            deg[node] = (int)sum;
        }
    }
    __syncthreads();
    for (int b = brow; b < NCH; b += 4) {
        if (node2 < NN)
            *(unsigned int*)(base + (size_t)b * NN + node2) =
                *(const unsigned int*)(&t16[b * 132 + colw * 2]);
    }
}

// ---------------- parallel scan (deg = real edges; dis = rsqrt(deg+1)) -----------
__global__ void k_scan1(const int* __restrict__ deg0, const int* __restrict__ deg1,
                        float* __restrict__ dis0, float* __restrict__ dis1,
                        int* __restrict__ bsum, int n) {
    int l = blockIdx.y;
    const int* deg = l ? deg1 : deg0;
    float* dis = l ? dis1 : dis0;
    int t = threadIdx.x;
    int base = blockIdx.x * 1024 + t * 4;
    int d[4] = {0, 0, 0, 0};
    if (base + 3 < n) {
        int4 q = *(const int4*)(deg + base);
        d[0] = q.x; d[1] = q.y; d[2] = q.z; d[3] = q.w;
    } else {
#pragma unroll
        for (int j = 0; j < 4; j++) if (base + j < n) d[j] = deg[base + j];
    }
#pragma unroll
    for (int j = 0; j < 4; j++)
        if (base + j < n) dis[base + j] = rsqrtf((float)(d[j] + 1));
    int s = d[0] + d[1] + d[2] + d[3];
#pragma unroll
    for (int off = 32; off >= 1; off >>= 1) s += __shfl_down(s, off, 64);
    __shared__ int ws[4];
    if ((t & 63) == 0) ws[t >> 6] = s;
    __syncthreads();
    if (t == 0) bsum[l * 64 + blockIdx.x] = ws[0] + ws[1] + ws[2] + ws[3];
}

__global__ void k_scan2(const int* __restrict__ bsum, int* __restrict__ boff) {
    int lane = threadIdx.x & 63;
    int l = threadIdx.x >> 6;
    int v = (lane < NB) ? bsum[l * 64 + lane] : 0;
    int s = v;
#pragma unroll
    for (int off = 1; off < 64; off <<= 1) {
        int u = __shfl_up(s, off, 64);
        if (lane >= off) s += u;
    }
    boff[l * 64 + lane] = s - v;   // exclusive
}

__global__ void k_scan3(const int* __restrict__ deg0, const int* __restrict__ deg1,
                        const int* __restrict__ boff,
                        int* __restrict__ cur0, int* __restrict__ cur1, int n) {
    int l = blockIdx.y;
    const int* deg = l ? deg1 : deg0;
    int* cur = l ? cur1 : cur0;
    int t = threadIdx.x;
    int base = blockIdx.x * 1024 + t * 4;
    int d[4] = {0, 0, 0, 0};
    if (base + 3 < n) {
        int4 q = *(const int4*)(deg + base);
        d[0] = q.x; d[1] = q.y; d[2] = q.z; d[3] = q.w;
    } else {
#pragma unroll
        for (int j = 0; j < 4; j++) if (base + j < n) d[j] = deg[base + j];
    }
    int s = d[0] + d[1] + d[2] + d[3];
    __shared__ int sc[256];
    sc[t] = s;
    __syncthreads();
    for (int off = 1; off < 256; off <<= 1) {
        int v = (t >= off) ? sc[t - off] : 0;
        __syncthreads();
        sc[t] += v;
        __syncthreads();
    }
    int p = boff[l * 64 + blockIdx.x] + sc[t] - s;   // exclusive prefix
#pragma unroll
    for (int j = 0; j < 4; j++) {
        if (base + j < n) { cur[base + j] = p; p += d[j]; }
    }
}

// ---------------- GEMM core: 64x128 tile, K=256, bf16 MFMA ----------------
__device__ __forceinline__ void gemm_core(const unsigned short* __restrict__ A,
                                          const unsigned short* __restrict__ wt,
                                          int row0, float4v acc[8]) {
    __shared__ short A_s[64 * 72];
    __shared__ short B_s[128 * 72];
    int tid = threadIdx.x;
    int lane = tid & 63, w = tid >> 6;
    int m = lane & 15, quad = lane >> 4;
#pragma unroll
    for (int t = 0; t < 8; t++) acc[t] = (float4v){0.f, 0.f, 0.f, 0.f};
    for (int c = 0; c < 4; c++) {
#pragma unroll
        for (int i = 0; i < 2; i++) {
            int e = (i * 256 + tid) * 8;
            int r = e >> 6, cc = e & 63;
            int rr = row0 + r;
            short8 v = {0, 0, 0, 0, 0, 0, 0, 0};
            if (rr < NN) v = *(const short8*)(A + rr * 256 + c * 64 + cc);
            *(short8*)&A_s[r * 72 + cc] = v;
        }
#pragma unroll
        for (int i = 0; i < 4; i++) {
            int e = (i * 256 + tid) * 8;
            int nr = e >> 6, kk = e & 63;
            *(short8*)&B_s[nr * 72 + kk] = *(const short8*)(wt + nr * 256 + c * 64 + kk);
        }
        __syncthreads();
#pragma unroll
        for (int c2 = 0; c2 < 2; c2++) {
            short8 a = *(short8*)&A_s[(w * 16 + m) * 72 + c2 * 32 + quad * 8];
#pragma unroll
            for (int t = 0; t < 8; t++) {
                short8 b = *(short8*)&B_s[(t * 16 + m) * 72 + c2 * 32 + quad * 8];
                acc[t] = __builtin_amdgcn_mfma_f32_16x16x32_bf16(a, b, acc[t], 0, 0, 0);
            }
        }
        __syncthreads();
    }
}

// ---- k_fillpe: FUSED edge-fill + PE GEMM (independent work) ----
// fill: position = cur[col] + base[chunk][col] + localrank[i], atomic-free.
__global__ __launch_bounds__(256)
void k_fillpe(const int* __restrict__ ei0, const void* __restrict__ ea0,
              const float* __restrict__ dis0, const int* __restrict__ cur0,
              const int* __restrict__ rank0, int4* __restrict__ edges0,
              const int* __restrict__ ei1, const void* __restrict__ ea1,
              const float* __restrict__ dis1, const int* __restrict__ cur1,
              const int* __restrict__ rank1, int4* __restrict__ edges1,
              const unsigned short* __restrict__ cnt,
              const unsigned short* __restrict__ xcat,
              const unsigned short* __restrict__ wt,
              unsigned short* __restrict__ xpe1, unsigned short* __restrict__ xpe2,
              const int* __restrict__ dflag) {
    int b = blockIdx.x;
    if (b < 2 * FILLB) {
        int lvl = b >= FILLB;
        const int* row = lvl ? ei1 : ei0;
        const int* col = row + NE;
        const void* attr = lvl ? ea1 : ea0;
        const float* dis = lvl ? dis1 : dis0;
        const int* cur = lvl ? cur1 : cur0;
        const int* rank = lvl ? rank1 : rank0;
        const unsigned short* base = cnt + (size_t)lvl * NCH * NN;
        int4* edges = lvl ? edges1 : edges0;
        int i0 = ((b - (lvl ? FILLB : 0)) * 256 + threadIdx.x) * 4;
        if (i0 >= NE) return;   // NE % 4 == 0 -> full quads only
        int4 rr = *(const int4*)(row + i0);
        int4 cc = *(const int4*)(col + i0);
        int4 rk = *(const int4*)(rank + i0);
        int isbf = dflag[0];
        float a[4];
        if (isbf) {
            unsigned short tmp[4];
            __builtin_memcpy(tmp, (const unsigned short*)attr + i0, 8);
#pragma unroll
            for (int j = 0; j < 4; j++) a[j] = bfbits_to_f(tmp[j]);
        } else {
            __builtin_memcpy(a, (const float*)attr + i0, 16);
        }
        int rv[4] = {rr.x, rr.y, rr.z, rr.w};
        int cv[4] = {cc.x, cc.y, cc.z, cc.w};
        int kv[4] = {rk.x, rk.y, rk.z, rk.w};
#pragma unroll
        for (int j = 0; j < 4; j++) {
            int blk = (i0 + j) / CHSZ;
            int p = cur[cv[j]] + (int)base[(size_t)blk * NN + cv[j]] + kv[j];
            float w2 = (a[j] > 0.f) ? fminf(rsqrtf(a[j]), 1.f) : 0.f;
            int4 rec;
            rec.x = rv[j];
            rec.y = f_as_i(dis[rv[j]] * dis[cv[j]]);
            rec.z = f_as_i(w2);
            rec.w = 0;
            edges[p] = rec;
        }
    } else {
        int g = b - 2 * FILLB;
        int y = g >= GX;
        int bx = g - (y ? GX : 0);
        float4v acc[8];
        gemm_core(xcat, wt + (y ? WSLOT : 0), bx * 64, acc);
        unsigned short* out = y ? xpe2 : xpe1;
        int lane = threadIdx.x & 63, w = threadIdx.x >> 6;
        int m = lane & 15, quad = lane >> 4;
        int row0 = bx * 64;
#pragma unroll
        for (int t = 0; t < 8; t++)
#pragma unroll
            for (int r = 0; r < 4; r++) {
                int row = row0 + w * 16 + quad * 4 + r;
                if (row < NN) out[row * DD + t * 16 + m] = f_to_bfbits(acc[t][r]);
            }
    }
}

// ---- double-layer GEMM: out = 0.5*relu(acatA@wtA) + 0.5*relu(acatB@wtB) ----
__global__ __launch_bounds__(256)
void k_gemmL2(const unsigned short* __restrict__ acatA,
              const unsigned short* __restrict__ wtA,
              const unsigned short* __restrict__ acatB,
              const unsigned short* __restrict__ wtB,
              unsigned short* __restrict__ outBf, void* __restrict__ outFinal,
              const int* __restrict__ dflag, int final_mode) {
    float4v accA[8], accB[8];
    gemm_core(acatA, wtA, blockIdx.x * 64, accA);
    gemm_core(acatB, wtB, blockIdx.x * 64, accB);
    int lane = threadIdx.x & 63, w = threadIdx.x >> 6;
    int m = lane & 15, quad = lane >> 4;
    int row0 = blockIdx.x * 64;
    int isbf = final_mode ? dflag[0] : 1;
#pragma unroll
    for (int t = 0; t < 8; t++) {
        int colc = t * 16 + m;
#pragma unroll
        for (int r = 0; r < 4; r++) {
            int row = row0 + w * 16 + quad * 4 + r;
            if (row >= NN) continue;
            float v = 0.5f * fmaxf(accA[t][r], 0.f) + 0.5f * fmaxf(accB[t][r], 0.f);
            if (final_mode && !isbf)
                ((float*)outFinal)[row * DD + colc] = v;
            else if (final_mode)
                ((unsigned short*)outFinal)[row * DD + colc] = f_to_bfbits(v);
            else
                outBf[row * DD + colc] = f_to_bfbits(v);
        }
    }
}

// ---------------- dual-level aggregation over X (a1|a2 -> acat[N,256]) ----------
// 1 wave per node, PAIR-PROCESSED (see round 8). cur[] holds START offsets.
__global__ __launch_bounds__(256)
void k_aggd(const int4* __restrict__ edges0, const int* __restrict__ cur0,
            const int* __restrict__ deg0, const float* __restrict__ dis0,
            const unsigned short* __restrict__ X0, unsigned short* __restrict__ acat0,
            const int4* __restrict__ edges1, const int* __restrict__ cur1,
            const int* __restrict__ deg1, const float* __restrict__ dis1,
            const unsigned short* __restrict__ X1, unsigned short* __restrict__ acat1) {
    int b = blockIdx.x;
    int lvl = b >= AGGB;
    const int4* edges = lvl ? edges1 : edges0;
    const int* cur = lvl ? cur1 : cur0;
    const int* deg = lvl ? deg1 : deg0;
    const float* dis = lvl ? dis1 : dis0;
    const unsigned short* X = lvl ? X1 : X0;
    unsigned short* acat = lvl ? acat1 : acat0;
    int wave = ((b - (lvl ? AGGB : 0)) * 256 + threadIdx.x) >> 6;
    int lane = threadIdx.x & 63;
    if (wave >= NN) return;
    int half = lane >> 5;
    int sub = lane & 31;
    int e0 = sub * 4;
    int start = cur[wave];
    int d = deg[wave];
    int end = start + d;
    float dn = dis[wave];
    float2v a1lo = {0.f, 0.f}, a1hi = {0.f, 0.f};
    float2v a2lo = {0.f, 0.f}, a2hi = {0.f, 0.f};
    int s = start;
    while (s < end) {
        int take = end - s;
        if (take > 64) take = 64;
        int li = s + lane;
        int4 rec = edges[(li < end) ? li : (end - 1)];
        for (int j0 = 0; j0 < take; j0 += 8) {
            int src[4];
            float w1[4], w2[4];
#pragma unroll
            for (int pp = 0; pp < 4; pp++) {
                int j = j0 + pp * 2 + half;
                src[pp] = __shfl(rec.x, j, 64);
                float ww1 = bits_to_f((unsigned int)__shfl(rec.y, j, 64));
                float ww2 = bits_to_f((unsigned int)__shfl(rec.z, j, 64));
                int ok = j < take;
                w1[pp] = ok ? ww1 : 0.f;
                w2[pp] = ok ? ww2 : 0.f;
            }
            uint2 q[4];
#pragma unroll
            for (int pp = 0; pp < 4; pp++)
                q[pp] = *(const uint2*)(X + src[pp] * DD + e0);
#pragma unroll
            for (int pp = 0; pp < 4; pp++) {
                float2v xa = { bits_to_f(q[pp].x << 16),
                               bits_to_f(q[pp].x & 0xFFFF0000u) };
                float2v xb = { bits_to_f(q[pp].y << 16),
                               bits_to_f(q[pp].y & 0xFFFF0000u) };
                a1lo += w1[pp] * xa;
                a1hi += w1[pp] * xb;
                a2lo += w2[pp] * xa;
                a2hi += w2[pp] * xb;
            }
        }
        s += take;
    }
    float2v sendlo = half ? a1lo : a2lo;
    float2v sendhi = half ? a1hi : a2hi;
    float2v keeplo = half ? a2lo : a1lo;
    float2v keephi = half ? a2hi : a1hi;
    float2v tlo, thi;
    tlo.x = keeplo.x + __shfl_xor(sendlo.x, 32, 64);
    tlo.y = keeplo.y + __shfl_xor(sendlo.y, 32, 64);
    thi.x = keephi.x + __shfl_xor(sendhi.x, 32, 64);
    thi.y = keephi.y + __shfl_xor(sendhi.y, 32, 64);
    uint2 qs = *(const uint2*)(X + wave * DD + e0);
    float f = half ? 1.0f : dn * dn;
    tlo.x += f * bits_to_f(qs.x << 16);
    tlo.y += f * bits_to_f(qs.x & 0xFFFF0000u);
    thi.x += f * bits_to_f(qs.y << 16);
    thi.y += f * bits_to_f(qs.y & 0xFFFF0000u);
    unsigned int p0 = (unsigned int)f_to_bfbits(tlo.x) |
                      ((unsigned int)f_to_bfbits(tlo.y) << 16);
    unsigned int p1 = (unsigned int)f_to_bfbits(thi.x) |
                      ((unsigned int)f_to_bfbits(thi.y) << 16);
    uint2 outv;
    outv.x = p0;
    outv.y = p1;
    *(uint2*)(acat + wave * 256 + half * 128 + e0) = outv;
}

// ---------------- Launch ----------------

#define PADUP(x) (((x) + 255) & ~(size_t)255)

extern "C" void kernel_launch(void* const* d_in, const int* in_sizes, int n_in,
                              void* d_out, int out_size, void* d_ws, size_t ws_size,
                              hipStream_t stream) {
    (void)in_sizes; (void)n_in; (void)out_size; (void)ws_size;

    const void* x    = d_in[0];
    const void* d2an = d_in[1];
    const int*  ei0  = (const int*)d_in[2];
    const void* ea0  = d_in[3];
    const int*  ei1  = (const int*)d_in[4];
    const void* ea1  = d_in[5];

    char* p = (char*)d_ws;
    unsigned short* xpe1 = (unsigned short*)p; p += PADUP((size_t)NN * DD * 2);
    unsigned short* xpe2 = (unsigned short*)p; p += PADUP((size_t)NN * DD * 2);
    unsigned short* xm   = (unsigned short*)p; p += PADUP((size_t)NN * DD * 2);
    unsigned short* xcat = (unsigned short*)p; p += PADUP((size_t)NN * 256 * 2);
    unsigned short* acat0 = xcat;              // xcat dead after PE GEMM
    unsigned short* acat1 = (unsigned short*)p; p += PADUP((size_t)NN * 256 * 2);
    unsigned short* wt   = (unsigned short*)p; p += PADUP((size_t)6 * WSLOT * 2);
    int*   deg0 = (int*)p;    p += PADUP((size_t)NN * 4);
    int*   cur0 = (int*)p;    p += PADUP((size_t)NN * 4);
    float* dis0 = (float*)p;  p += PADUP((size_t)NN * 4);
    int*   deg1 = (int*)p;    p += PADUP((size_t)NN * 4);
    int*   cur1 = (int*)p;    p += PADUP((size_t)NN * 4);
    float* dis1 = (float*)p;  p += PADUP((size_t)NN * 4);
    int4*  edges0 = (int4*)p; p += PADUP((size_t)NE * 16);
    int4*  edges1 = (int4*)p; p += PADUP((size_t)NE * 16);
    int*   bsum = (int*)p;    p += PADUP((size_t)128 * 4);
    int*   boff = (int*)p;    p += PADUP((size_t)128 * 4);
    int*   rank0 = (int*)p;   p += PADUP((size_t)NE * 4);   // dedicated: fill runs
    int*   rank1 = (int*)p;   p += PADUP((size_t)NE * 4);   // concurrent w/ PE GEMM
    int*   dflag = (int*)p;

    // cnt matrix [2][NCH][NN] u16 = 25.6MB aliases acat1 (dead until step 7,
    // and fill (last cnt reader) completes before k_aggd writes acat1).
    unsigned short* cnt = acat1;

    // 1. dtype detect
    k_detect0<<<1, 256, 0, stream>>>((const unsigned int*)x, dflag, (float*)d_out);
    // 2. LDS-hist(+rank) + prepx + weight prep — ZERO global atomics
    kB<<<2 * NCH + PREPXB + PREPB, 256, 0, stream>>>(
        ei0, ei1, rank0, rank1, cnt, x, d2an, xcat,
        d_in[6], d_in[7], d_in[8], d_in[9], d_in[10], d_in[11], d_in[12],
        d_in[13], d_in[14], d_in[15], wt, dflag);
    // 3. per-node block-prefix (cnt -> base, deg)
    k_scanB<<<dim3(SCANBB, 2), 256, 0, stream>>>(cnt, deg0, deg1);
    // 4-6. node prefix scan (cur from deg) + dis
    k_scan1<<<dim3(NB, 2), 256, 0, stream>>>(deg0, deg1, dis0, dis1, bsum, NN);
    k_scan2<<<1, 128, 0, stream>>>(bsum, boff);
    k_scan3<<<dim3(NB, 2), 256, 0, stream>>>(deg0, deg1, boff, cur0, cur1, NN);
    // 7. FUSED: edge fill (atomic-free, via base+rank) + PE GEMM
    k_fillpe<<<2 * FILLB + 2 * GX, 256, 0, stream>>>(
        ei0, ea0, dis0, cur0, rank0, edges0,
        ei1, ea1, dis1, cur1, rank1, edges1,
        cnt, xcat, wt, xpe1, xpe2, dflag);
    // 8. dual agg round 1: acat0 = agg0(xpe1), acat1 = agg1(xpe2)
    k_aggd<<<2 * AGGB, 256, 0, stream>>>(edges0, cur0, deg0, dis0, xpe1, acat0,
                                         edges1, cur1, deg1, dis1, xpe2, acat1);
    // 9. xm = 0.5*relu(acat0@W1) + 0.5*relu(acat1@W2)
    k_gemmL2<<<GX, 256, 0, stream>>>(acat0, wt + 2 * WSLOT,
                                     acat1, wt + 3 * WSLOT,
                                     xm, (void*)0, dflag, 0);
    // 10. dual agg round 2: acat0 = agg0(xm), acat1 = agg1(xm)
    k_aggd<<<2 * AGGB, 256, 0, stream>>>(edges0, cur0, deg0, dis0, xm, acat0,
                                         edges1, cur1, deg1, dis1, xm, acat1);
    // 11. out = 0.5*relu(acat0@W3) + 0.5*relu(acat1@W4)  (bf16/f32 per dflag)
    k_gemmL2<<<GX, 256, 0, stream>>>(acat0, wt + 4 * WSLOT,
                                     acat1, wt + 5 * WSLOT,
                                     (unsigned short*)0, d_out, dflag, 1);
}